// Round 8
// baseline (4852.571 us; speedup 1.0000x reference)
//
#include <hip/hip_runtime.h>
#include <hip/hip_fp16.h>

// LSTM: 4 layers, T=512, B=256, INPUT=100, H=128, gates=512 (i,f,g,o)
// Round 7: MFMA recurrent scan.
//   Diagnosis r1-r6: allocator places per-thread weight arrays in AGPRs
//   (VGPR_Count 84/48/88 < declared), gfx950 VALU can't read AGPR sources
//   (r5 assembler error) -> every weight use = v_accvgpr_read + op; scan was
//   issue-bound on the hidden movs (466/332 insts/step back-computed).
//   Fix: weights AS MFMA A-fragments -- MFMA reads AGPRs natively.
//   Structure: 16 blocks x 512 thr; block = 16 batch rows; wave w = units
//   [16w,16w+16) x 4 gates (64 Whh rows = 16 half8 A-frags, "+a"-pinned).
//   Per step: 4x ds_read_b128 of h^T f16 (XOR-swizzled [16][128] LDS),
//   16x mfma_f32_16x16x32_f16 (C-in = xg fragment, fp32), in-register
//   activations (lane owns 4 (unit,row) pairs), ds_write_b64 h, 1 barrier.
//   gemm_xg: unchanged math; store re-laid-out to scan fragment order.
// ws: io 67MB | xg2 33.5MB | hstate,cstate 256KB | wh16 512KB => ~101.4MB

#define TSTEPS 512
#define BATCH  256
#define HID    128
#define GATES  512
#define TC     64

typedef _Float16 half8 __attribute__((ext_vector_type(8)));
typedef float f32x4 __attribute__((ext_vector_type(4)));

__device__ __forceinline__ float sigmoid_f(float x) {
    return 1.0f / (1.0f + __expf(-x));
}
__device__ __forceinline__ float tanh_f(float x) {
    float e = __expf(2.0f * x);
    return 1.0f - 2.0f / (e + 1.0f);
}

// ---------------- Whh f16 pack: [layer][512 rows][128] row-major ----------
__global__ __launch_bounds__(256)
void pack_whh(const float* __restrict__ W0, const float* __restrict__ W1,
              const float* __restrict__ W2, const float* __restrict__ W3,
              unsigned short* __restrict__ out)
{
    int F = blockIdx.x * 256 + threadIdx.x;   // [0, 262144)
    int l = F >> 16;
    int rem = F & 65535;
    const float* W = (l == 0) ? W0 : (l == 1) ? W1 : (l == 2) ? W2 : W3;
    __half h = __float2half_rn(W[rem]);
    out[F] = __half_as_ushort(h);
}

// ---------------- input-projection GEMM (fp32) ----------------
// Math unchanged; store goes to xg2 in scan-fragment order:
// idx = ((q*16 + b>>4)*512 + sctid)*16 + g*4 + r,
// sctid = (u>>4)*64 + ((u>>2)&3)*16 + (b&15), j = g*128+u.
template<int K, bool L0>
__global__ __launch_bounds__(256, 4)
void gemm_xg(const float* __restrict__ A, const float* __restrict__ W,
             const float* __restrict__ bih, const float* __restrict__ bhh,
             float* __restrict__ XG, int t0)
{
    __shared__ float As[32][68];
    __shared__ float Bs[32][68];
    const int tid  = threadIdx.x;
    const int flat = blockIdx.y * 8 + blockIdx.x;
    const int rt   = flat & 255;
    const int ct   = flat >> 8;
    const int j0   = ct * 64;
    const int R0   = rt * 64;
    const int ty = tid >> 4, tx = tid & 15;

    float acc[4][4] = {};

    for (int kt = 0; kt < K; kt += 32) {
        #pragma unroll
        for (int i = 0; i < 8; ++i) {
            int f  = tid + 256 * i;
            int r  = f >> 5, kk = f & 31;
            int k  = kt + kk;
            int Rg = R0 + r;
            int q  = Rg >> 8, b = Rg & 255;
            float av = 0.f, wv = 0.f;
            if (K == 128 || k < K) {
                av = L0 ? A[(b * TSTEPS + (t0 + q)) * K + k]
                        : A[((t0 + q) * BATCH + b) * K + k];
                wv = W[(j0 + r) * K + k];
            }
            As[kk][r] = av;
            Bs[kk][r] = wv;
        }
        __syncthreads();
        #pragma unroll 8
        for (int kk = 0; kk < 32; ++kk) {
            float4 a4 = *(const float4*)&As[kk][ty * 4];
            float4 b4 = *(const float4*)&Bs[kk][tx * 4];
            float aa[4] = {a4.x, a4.y, a4.z, a4.w};
            float bb[4] = {b4.x, b4.y, b4.z, b4.w};
            #pragma unroll
            for (int ii = 0; ii < 4; ++ii)
                #pragma unroll
                for (int jj = 0; jj < 4; ++jj)
                    acc[ii][jj] = fmaf(aa[ii], bb[jj], acc[ii][jj]);
        }
        __syncthreads();
    }

    float4 bi = *(const float4*)&bih[j0 + tx * 4];
    float4 bh = *(const float4*)&bhh[j0 + tx * 4];
    float bsum[4] = {bi.x + bh.x, bi.y + bh.y, bi.z + bh.z, bi.w + bh.w};
    const int j = j0 + tx * 4;         // 4-aligned, same (g,w,s) for all 4 r
    const int g = j >> 7, u = j & 127;
    const int ws_ = (u >> 4) * 64 + ((u >> 2) & 3) * 16;
    #pragma unroll
    for (int ii = 0; ii < 4; ++ii) {
        int Rg = R0 + ty * 4 + ii;
        int q = Rg >> 8, b = Rg & 255;
        float4 st = {acc[ii][0] + bsum[0], acc[ii][1] + bsum[1],
                     acc[ii][2] + bsum[2], acc[ii][3] + bsum[3]};
        size_t idx = (((size_t)q * 16 + (b >> 4)) * 512 + ws_ + (b & 15)) * 16 + g * 4;
        *(float4*)&XG[idx] = st;
    }
}

// ---------------- MFMA recurrent scan ----------------
// 16 blocks x 512 thr. Block: batch rows [16*B16, +16). Wave w: units
// [16w, 16w+16), all 4 gates. Lane l: supplies A row t15=l&15, receives
// D (col=t15 batch row, units 16w+4s+r, s=(l>>4)&3, r=reg).
__global__ __attribute__((amdgpu_waves_per_eu(2, 2))) __launch_bounds__(512)
void lstm_rec(const float* __restrict__ XG, const unsigned short* __restrict__ WH,
              float* __restrict__ Hout,
              float* __restrict__ hstate, float* __restrict__ cstate,
              int t0, int first)
{
    const int tid = threadIdx.x;
    const int w   = tid >> 6;
    const int l   = tid & 63;
    const int s   = l >> 4;
    const int t15 = l & 15;
    const int B16 = blockIdx.x;
    const int rb  = B16 * 16 + t15;
    const int u0  = 16 * w + 4 * s;

    // h^T in LDS, f16 [16 rows][128 units], 16B-chunk XOR swizzle by (row&7)
    __shared__ unsigned short hbuf[2][2048];

    // A-frags: Whh[g*128 + 16w + t15][kt*32 + s*8 ..+8) -> 16 half8 (64 regs)
    half8 wA[16];
    #pragma unroll
    for (int g = 0; g < 4; ++g)
        #pragma unroll
        for (int kt = 0; kt < 4; ++kt) {
            int row = g * 128 + 16 * w + t15;
            wA[g * 4 + kt] = *(const half8*)(WH + row * 128 + kt * 32 + s * 8);
        }
    #pragma unroll
    for (int i = 0; i < 16; ++i)
        asm volatile("" : "+a"(wA[i]));   // pin in AGPR class (MFMA-native)

    float c0, c1, c2, c3, h0, h1, h2, h3;
    if (first) {
        c0 = c1 = c2 = c3 = 0.f;
        h0 = h1 = h2 = h3 = 0.f;
    } else {
        f32x4 cv = *(const f32x4*)(cstate + rb * HID + u0);
        c0 = cv[0]; c1 = cv[1]; c2 = cv[2]; c3 = cv[3];
        f32x4 hv = *(const f32x4*)(hstate + rb * HID + u0);
        h0 = hv[0]; h1 = hv[1]; h2 = hv[2]; h3 = hv[3];
    }

    // write byte offset (8B): chunk = 2w + (s>>1), XOR (t15&7), +8*(s&1)
    const int woff = t15 * 256 + (((2 * w + (s >> 1)) ^ (t15 & 7)) << 4) + (s & 1) * 8;
    int roff[4];
    #pragma unroll
    for (int kt = 0; kt < 4; ++kt)
        roff[kt] = t15 * 256 + (((4 * kt + s) ^ (t15 & 7)) << 4);

    {   // initial h -> hbuf[0]
        __half2 pa = __floats2half2_rn(h0, h1);
        __half2 pb = __floats2half2_rn(h2, h3);
        uint2 v = { *(unsigned int*)&pa, *(unsigned int*)&pb };
        *(uint2*)((char*)&hbuf[0][0] + woff) = v;
    }
    __syncthreads();

    const float* xgp = XG + (size_t)B16 * 8192 + (size_t)tid * 16;
    f32x4 xc[4], xn[4];
    #pragma unroll
    for (int g = 0; g < 4; ++g) xc[g] = *(const f32x4*)(xgp + g * 4);

    int ct = 0;
    for (int st = 0; st < TC; ++st) {
        if (st + 1 < TC) {
            const float* xp = xgp + (size_t)(st + 1) * 131072;
            #pragma unroll
            for (int g = 0; g < 4; ++g) xn[g] = *(const f32x4*)(xp + g * 4);
        }
        // B-frags: h^T[k = 32kt+8s+j][col = t15]
        char* hb = (char*)&hbuf[ct][0];
        half8 bf0 = *(const half8*)(hb + roff[0]);
        half8 bf1 = *(const half8*)(hb + roff[1]);
        half8 bf2 = *(const half8*)(hb + roff[2]);
        half8 bf3 = *(const half8*)(hb + roff[3]);

        f32x4 a0 = xc[0], a1 = xc[1], a2 = xc[2], a3 = xc[3];
        a0 = __builtin_amdgcn_mfma_f32_16x16x32_f16(wA[0],  bf0, a0, 0, 0, 0);
        a1 = __builtin_amdgcn_mfma_f32_16x16x32_f16(wA[4],  bf0, a1, 0, 0, 0);
        a2 = __builtin_amdgcn_mfma_f32_16x16x32_f16(wA[8],  bf0, a2, 0, 0, 0);
        a3 = __builtin_amdgcn_mfma_f32_16x16x32_f16(wA[12], bf0, a3, 0, 0, 0);
        a0 = __builtin_amdgcn_mfma_f32_16x16x32_f16(wA[1],  bf1, a0, 0, 0, 0);
        a1 = __builtin_amdgcn_mfma_f32_16x16x32_f16(wA[5],  bf1, a1, 0, 0, 0);
        a2 = __builtin_amdgcn_mfma_f32_16x16x32_f16(wA[9],  bf1, a2, 0, 0, 0);
        a3 = __builtin_amdgcn_mfma_f32_16x16x32_f16(wA[13], bf1, a3, 0, 0, 0);
        a0 = __builtin_amdgcn_mfma_f32_16x16x32_f16(wA[2],  bf2, a0, 0, 0, 0);
        a1 = __builtin_amdgcn_mfma_f32_16x16x32_f16(wA[6],  bf2, a1, 0, 0, 0);
        a2 = __builtin_amdgcn_mfma_f32_16x16x32_f16(wA[10], bf2, a2, 0, 0, 0);
        a3 = __builtin_amdgcn_mfma_f32_16x16x32_f16(wA[14], bf2, a3, 0, 0, 0);
        a0 = __builtin_amdgcn_mfma_f32_16x16x32_f16(wA[3],  bf3, a0, 0, 0, 0);
        a1 = __builtin_amdgcn_mfma_f32_16x16x32_f16(wA[7],  bf3, a1, 0, 0, 0);
        a2 = __builtin_amdgcn_mfma_f32_16x16x32_f16(wA[11], bf3, a2, 0, 0, 0);
        a3 = __builtin_amdgcn_mfma_f32_16x16x32_f16(wA[15], bf3, a3, 0, 0, 0);

        // activations: a0=i, a1=f, a2=g, a3=o ; lane pair r -> unit u0+r
        c0 = sigmoid_f(a1[0]) * c0 + sigmoid_f(a0[0]) * tanh_f(a2[0]);
        h0 = sigmoid_f(a3[0]) * tanh_f(c0);
        c1 = sigmoid_f(a1[1]) * c1 + sigmoid_f(a0[1]) * tanh_f(a2[1]);
        h1 = sigmoid_f(a3[1]) * tanh_f(c1);
        c2 = sigmoid_f(a1[2]) * c2 + sigmoid_f(a0[2]) * tanh_f(a2[2]);
        h2 = sigmoid_f(a3[2]) * tanh_f(c2);
        c3 = sigmoid_f(a1[3]) * c3 + sigmoid_f(a0[3]) * tanh_f(a2[3]);
        h3 = sigmoid_f(a3[3]) * tanh_f(c3);

        {   // h -> hbuf[ct^1] (packed f16, swizzled)
            __half2 pa = __floats2half2_rn(h0, h1);
            __half2 pb = __floats2half2_rn(h2, h3);
            uint2 v = { *(unsigned int*)&pa, *(unsigned int*)&pb };
            *(uint2*)((char*)&hbuf[ct ^ 1][0] + woff) = v;
        }
        // h -> global io (fp32)
        f32x4 hv = {h0, h1, h2, h3};
        *(f32x4*)(Hout + ((size_t)(t0 + st) * BATCH + rb) * HID + u0) = hv;

        __syncthreads();
        ct ^= 1;
        #pragma unroll
        for (int g = 0; g < 4; ++g) xc[g] = xn[g];
    }

    f32x4 cv = {c0, c1, c2, c3};
    f32x4 hv = {h0, h1, h2, h3};
    *(f32x4*)(cstate + rb * HID + u0) = cv;
    *(f32x4*)(hstate + rb * HID + u0) = hv;
}

// ---------------- final FC ----------------
__global__ __launch_bounds__(512)
void fc_kernel(const float* __restrict__ hstate, const float* __restrict__ fcw,
               const float* __restrict__ fcb, float* __restrict__ out)
{
    int idx = threadIdx.x;      // 512 = 256 rows x 2 outs
    int b = idx >> 1, o = idx & 1;
    float acc = fcb[o];
    #pragma unroll
    for (int k = 0; k < HID; ++k)
        acc = fmaf(hstate[b * HID + k], fcw[o * HID + k], acc);
    out[b * 2 + o] = acc;
}

extern "C" void kernel_launch(void* const* d_in, const int* in_sizes, int n_in,
                              void* d_out, int out_size, void* d_ws, size_t ws_size,
                              hipStream_t stream)
{
    const float* x = (const float*)d_in[0];
    const float* w_ih[4]; const float* w_hh[4];
    const float* b_ih[4]; const float* b_hh[4];
    for (int l = 0; l < 4; ++l) {
        w_ih[l] = (const float*)d_in[1 + 4 * l];
        w_hh[l] = (const float*)d_in[2 + 4 * l];
        b_ih[l] = (const float*)d_in[3 + 4 * l];
        b_hh[l] = (const float*)d_in[4 + 4 * l];
    }
    const float* fc_w = (const float*)d_in[17];
    const float* fc_b = (const float*)d_in[18];
    float* out = (float*)d_out;

    char* wsb = (char*)d_ws;
    float* io  = (float*)wsb;                                   // 67,108,864 B
    float* xg  = (float*)(wsb + 67108864);                      // 33,554,432 B
    float* hst = (float*)(wsb + 67108864 + 33554432);           // 131,072 B
    float* cst = hst + BATCH * HID;                             // 131,072 B
    unsigned short* wh16 = (unsigned short*)(wsb + 67108864 + 33554432 + 262144); // 524,288 B

    // one-time f16 pack of all 4 Whh: [l][512][128]
    pack_whh<<<1024, 256, 0, stream>>>(w_hh[0], w_hh[1], w_hh[2], w_hh[3], wh16);

    dim3 ggrid(8, 256);
    for (int lyr = 0; lyr < 4; ++lyr) {
        const unsigned short* whl = wh16 + (size_t)lyr * 65536;
        for (int cchunk = 0; cchunk < TSTEPS / TC; ++cchunk) {
            int t0 = cchunk * TC;
            if (lyr == 0)
                gemm_xg<100, true><<<ggrid, 256, 0, stream>>>(x, w_ih[0], b_ih[0], b_hh[0], xg, t0);
            else
                gemm_xg<128, false><<<ggrid, 256, 0, stream>>>(io, w_ih[lyr], b_ih[lyr], b_hh[lyr], xg, t0);
            lstm_rec<<<16, 512, 0, stream>>>(xg, whl, io, hst, cst, t0, cchunk == 0 ? 1 : 0);
        }
    }
    fc_kernel<<<1, 512, 0, stream>>>(hst, fc_w, fc_b, out);
}

// Round 9
// 4458.698 us; speedup vs baseline: 1.0883x; 1.0883x over previous
//
#include <hip/hip_runtime.h>
#include <hip/hip_fp16.h>

// LSTM: 4 layers, T=512, B=256, INPUT=100, H=128, gates=512 (i,f,g,o)
// Round 8: MFMA scan + non-draining barriers.
//   r7 post-mortem: __syncthreads() drains vmcnt(0) every step -> xg
//   prefetch latency exposed per step (1.64us/step vs ~0.25 floor). Fix:
//   raw s_barrier with lgkmcnt(0)-only wait (HK/m201 pattern) so global
//   loads stay in flight across steps; depth-2 prefetch (2x-unrolled loop,
//   named frag sets); gemm_xg reverted to coalesced store (r7's scatter
//   store cost ~18us/dispatch) -- scan reads xg in natural layout.
// ws: io 67MB | xg 33.5MB | hstate,cstate 256KB | wh16 512KB => ~101.4MB

#define TSTEPS 512
#define BATCH  256
#define HID    128
#define GATES  512
#define TC     64

typedef _Float16 half8 __attribute__((ext_vector_type(8)));
typedef float f32x4 __attribute__((ext_vector_type(4)));

__device__ __forceinline__ float sigmoid_f(float x) {
    return 1.0f / (1.0f + __expf(-x));
}
__device__ __forceinline__ float tanh_f(float x) {
    float e = __expf(2.0f * x);
    return 1.0f - 2.0f / (e + 1.0f);
}

// ---------------- Whh f16 pack: [layer][512 rows][128] row-major ----------
__global__ __launch_bounds__(256)
void pack_whh(const float* __restrict__ W0, const float* __restrict__ W1,
              const float* __restrict__ W2, const float* __restrict__ W3,
              unsigned short* __restrict__ out)
{
    int F = blockIdx.x * 256 + threadIdx.x;   // [0, 262144)
    int l = F >> 16;
    int rem = F & 65535;
    const float* W = (l == 0) ? W0 : (l == 1) ? W1 : (l == 2) ? W2 : W3;
    __half h = __float2half_rn(W[rem]);
    out[F] = __half_as_ushort(h);
}

// ---------------- input-projection GEMM (fp32, coalesced store) ----------
template<int K, bool L0>
__global__ __launch_bounds__(256, 4)
void gemm_xg(const float* __restrict__ A, const float* __restrict__ W,
             const float* __restrict__ bih, const float* __restrict__ bhh,
             float* __restrict__ XG, int t0)
{
    __shared__ float As[32][68];
    __shared__ float Bs[32][68];
    const int tid  = threadIdx.x;
    const int flat = blockIdx.y * 8 + blockIdx.x;
    const int rt   = flat & 255;
    const int ct   = flat >> 8;
    const int j0   = ct * 64;
    const int R0   = rt * 64;
    const int ty = tid >> 4, tx = tid & 15;

    float acc[4][4] = {};

    for (int kt = 0; kt < K; kt += 32) {
        #pragma unroll
        for (int i = 0; i < 8; ++i) {
            int f  = tid + 256 * i;
            int r  = f >> 5, kk = f & 31;
            int k  = kt + kk;
            int Rg = R0 + r;
            int q  = Rg >> 8, b = Rg & 255;
            float av = 0.f, wv = 0.f;
            if (K == 128 || k < K) {
                av = L0 ? A[(b * TSTEPS + (t0 + q)) * K + k]
                        : A[((t0 + q) * BATCH + b) * K + k];
                wv = W[(j0 + r) * K + k];
            }
            As[kk][r] = av;
            Bs[kk][r] = wv;
        }
        __syncthreads();
        #pragma unroll 8
        for (int kk = 0; kk < 32; ++kk) {
            float4 a4 = *(const float4*)&As[kk][ty * 4];
            float4 b4 = *(const float4*)&Bs[kk][tx * 4];
            float aa[4] = {a4.x, a4.y, a4.z, a4.w};
            float bb[4] = {b4.x, b4.y, b4.z, b4.w};
            #pragma unroll
            for (int ii = 0; ii < 4; ++ii)
                #pragma unroll
                for (int jj = 0; jj < 4; ++jj)
                    acc[ii][jj] = fmaf(aa[ii], bb[jj], acc[ii][jj]);
        }
        __syncthreads();
    }

    float4 bi = *(const float4*)&bih[j0 + tx * 4];
    float4 bh = *(const float4*)&bhh[j0 + tx * 4];
    float bsum[4] = {bi.x + bh.x, bi.y + bh.y, bi.z + bh.z, bi.w + bh.w};
    #pragma unroll
    for (int ii = 0; ii < 4; ++ii) {
        int Rg = R0 + ty * 4 + ii;
        float4 st = {acc[ii][0] + bsum[0], acc[ii][1] + bsum[1],
                     acc[ii][2] + bsum[2], acc[ii][3] + bsum[3]};
        *(float4*)&XG[(size_t)Rg * GATES + j0 + tx * 4] = st;
    }
}

// ---------------- MFMA recurrent scan ----------------
// 16 blocks x 512 thr. Block: batch rows [16*B16, +16). Wave w: units
// [16w,16w+16) x 4 gates. A-frags (Whh) pinned in AGPRs. xg C-in read from
// natural layout. Raw barrier: lgkmcnt(0) only -- global loads pipelined
// across steps (vmcnt never drained in-loop).
__global__ __attribute__((amdgpu_waves_per_eu(2, 2))) __launch_bounds__(512)
void lstm_rec(const float* __restrict__ XG, const unsigned short* __restrict__ WH,
              float* __restrict__ Hout,
              float* __restrict__ hstate, float* __restrict__ cstate,
              int t0, int first)
{
    const int tid = threadIdx.x;
    const int w   = tid >> 6;
    const int l   = tid & 63;
    const int s   = l >> 4;
    const int t15 = l & 15;
    const int B16 = blockIdx.x;
    const int rb  = B16 * 16 + t15;
    const int u0  = 16 * w + 4 * s;

    // h^T in LDS, f16 [16 rows][128 units], 16B-chunk XOR swizzle by (row&7)
    __shared__ unsigned short hbuf[2][2048];

    // A-frags: Whh[g*128 + 16w + t15][kt*32 + s*8 ..+8) -> 16 half8 (64 regs)
    half8 wA[16];
    #pragma unroll
    for (int g = 0; g < 4; ++g)
        #pragma unroll
        for (int kt = 0; kt < 4; ++kt) {
            int row = g * 128 + 16 * w + t15;
            wA[g * 4 + kt] = *(const half8*)(WH + row * 128 + kt * 32 + s * 8);
        }
    #pragma unroll
    for (int i = 0; i < 16; ++i)
        asm volatile("" : "+a"(wA[i]));   // pin in AGPR class (MFMA-native)

    float c0, c1, c2, c3, h0, h1, h2, h3;
    if (first) {
        c0 = c1 = c2 = c3 = 0.f;
        h0 = h1 = h2 = h3 = 0.f;
    } else {
        f32x4 cv = *(const f32x4*)(cstate + rb * HID + u0);
        c0 = cv[0]; c1 = cv[1]; c2 = cv[2]; c3 = cv[3];
        f32x4 hv = *(const f32x4*)(hstate + rb * HID + u0);
        h0 = hv[0]; h1 = hv[1]; h2 = hv[2]; h3 = hv[3];
    }

    const int woff = t15 * 256 + (((2 * w + (s >> 1)) ^ (t15 & 7)) << 4) + (s & 1) * 8;
    int roff[4];
    #pragma unroll
    for (int kt = 0; kt < 4; ++kt)
        roff[kt] = t15 * 256 + (((4 * kt + s) ^ (t15 & 7)) << 4);

    {   // initial h -> hbuf[0]
        __half2 pa = __floats2half2_rn(h0, h1);
        __half2 pb = __floats2half2_rn(h2, h3);
        uint2 v = { *(unsigned int*)&pa, *(unsigned int*)&pb };
        *(uint2*)((char*)&hbuf[0][0] + woff) = v;
    }
    asm volatile("s_waitcnt lgkmcnt(0)" ::: "memory");
    __builtin_amdgcn_s_barrier();
    asm volatile("" ::: "memory");

    // xg C-in: natural layout, float4 at (q*256+rb)*512 + g*128 + u0
    const float* xgp = XG + (size_t)rb * GATES + u0;
    f32x4 xe[4], xo[4];
    #pragma unroll
    for (int g = 0; g < 4; ++g) xe[g] = *(const f32x4*)(xgp + g * 128);
    #pragma unroll
    for (int g = 0; g < 4; ++g) xo[g] = *(const f32x4*)(xgp + 131072 + g * 128);

// One LSTM step. RBUF/WBUF: LDS read/write buffer index. XF: named C-in
// frag set; prefetched (ST+2) after consumption -> ~1.5 steps in flight.
#define STEP(ST, RBUF, WBUF, XF)                                              \
    {                                                                         \
        char* hb = (char*)&hbuf[RBUF][0];                                     \
        half8 bf0 = *(const half8*)(hb + roff[0]);                            \
        half8 bf1 = *(const half8*)(hb + roff[1]);                            \
        half8 bf2 = *(const half8*)(hb + roff[2]);                            \
        half8 bf3 = *(const half8*)(hb + roff[3]);                            \
        f32x4 a0 = XF[0], a1 = XF[1], a2 = XF[2], a3 = XF[3];                 \
        a0 = __builtin_amdgcn_mfma_f32_16x16x32_f16(wA[0],  bf0, a0, 0, 0, 0);\
        a1 = __builtin_amdgcn_mfma_f32_16x16x32_f16(wA[4],  bf0, a1, 0, 0, 0);\
        a2 = __builtin_amdgcn_mfma_f32_16x16x32_f16(wA[8],  bf0, a2, 0, 0, 0);\
        a3 = __builtin_amdgcn_mfma_f32_16x16x32_f16(wA[12], bf0, a3, 0, 0, 0);\
        a0 = __builtin_amdgcn_mfma_f32_16x16x32_f16(wA[1],  bf1, a0, 0, 0, 0);\
        a1 = __builtin_amdgcn_mfma_f32_16x16x32_f16(wA[5],  bf1, a1, 0, 0, 0);\
        a2 = __builtin_amdgcn_mfma_f32_16x16x32_f16(wA[9],  bf1, a2, 0, 0, 0);\
        a3 = __builtin_amdgcn_mfma_f32_16x16x32_f16(wA[13], bf1, a3, 0, 0, 0);\
        a0 = __builtin_amdgcn_mfma_f32_16x16x32_f16(wA[2],  bf2, a0, 0, 0, 0);\
        a1 = __builtin_amdgcn_mfma_f32_16x16x32_f16(wA[6],  bf2, a1, 0, 0, 0);\
        a2 = __builtin_amdgcn_mfma_f32_16x16x32_f16(wA[10], bf2, a2, 0, 0, 0);\
        a3 = __builtin_amdgcn_mfma_f32_16x16x32_f16(wA[14], bf2, a3, 0, 0, 0);\
        a0 = __builtin_amdgcn_mfma_f32_16x16x32_f16(wA[3],  bf3, a0, 0, 0, 0);\
        a1 = __builtin_amdgcn_mfma_f32_16x16x32_f16(wA[7],  bf3, a1, 0, 0, 0);\
        a2 = __builtin_amdgcn_mfma_f32_16x16x32_f16(wA[11], bf3, a2, 0, 0, 0);\
        a3 = __builtin_amdgcn_mfma_f32_16x16x32_f16(wA[15], bf3, a3, 0, 0, 0);\
        if ((ST) + 2 < TC) {                                                  \
            const float* xp = xgp + (size_t)((ST) + 2) * 131072;              \
            XF[0] = *(const f32x4*)(xp);                                      \
            XF[1] = *(const f32x4*)(xp + 128);                                \
            XF[2] = *(const f32x4*)(xp + 256);                                \
            XF[3] = *(const f32x4*)(xp + 384);                                \
        }                                                                     \
        c0 = sigmoid_f(a1[0]) * c0 + sigmoid_f(a0[0]) * tanh_f(a2[0]);        \
        h0 = sigmoid_f(a3[0]) * tanh_f(c0);                                   \
        c1 = sigmoid_f(a1[1]) * c1 + sigmoid_f(a0[1]) * tanh_f(a2[1]);        \
        h1 = sigmoid_f(a3[1]) * tanh_f(c1);                                   \
        c2 = sigmoid_f(a1[2]) * c2 + sigmoid_f(a0[2]) * tanh_f(a2[2]);        \
        h2 = sigmoid_f(a3[2]) * tanh_f(c2);                                   \
        c3 = sigmoid_f(a1[3]) * c3 + sigmoid_f(a0[3]) * tanh_f(a2[3]);        \
        h3 = sigmoid_f(a3[3]) * tanh_f(c3);                                   \
        {                                                                     \
            __half2 pa = __floats2half2_rn(h0, h1);                           \
            __half2 pb = __floats2half2_rn(h2, h3);                           \
            uint2 v = { *(unsigned int*)&pa, *(unsigned int*)&pb };           \
            *(uint2*)((char*)&hbuf[WBUF][0] + woff) = v;                      \
        }                                                                     \
        f32x4 hv = {h0, h1, h2, h3};                                          \
        *(f32x4*)(Hout + ((size_t)(t0 + (ST)) * BATCH + rb) * HID + u0) = hv; \
        asm volatile("s_waitcnt lgkmcnt(0)" ::: "memory");                    \
        __builtin_amdgcn_s_barrier();                                         \
        asm volatile("" ::: "memory");                                        \
    }

    for (int st = 0; st < TC; st += 2) {
        STEP(st,     0, 1, xe);
        STEP(st + 1, 1, 0, xo);
    }
#undef STEP

    f32x4 cv = {c0, c1, c2, c3};
    f32x4 hv = {h0, h1, h2, h3};
    *(f32x4*)(cstate + rb * HID + u0) = cv;
    *(f32x4*)(hstate + rb * HID + u0) = hv;
}

// ---------------- final FC ----------------
__global__ __launch_bounds__(512)
void fc_kernel(const float* __restrict__ hstate, const float* __restrict__ fcw,
               const float* __restrict__ fcb, float* __restrict__ out)
{
    int idx = threadIdx.x;      // 512 = 256 rows x 2 outs
    int b = idx >> 1, o = idx & 1;
    float acc = fcb[o];
    #pragma unroll
    for (int k = 0; k < HID; ++k)
        acc = fmaf(hstate[b * HID + k], fcw[o * HID + k], acc);
    out[b * 2 + o] = acc;
}

extern "C" void kernel_launch(void* const* d_in, const int* in_sizes, int n_in,
                              void* d_out, int out_size, void* d_ws, size_t ws_size,
                              hipStream_t stream)
{
    const float* x = (const float*)d_in[0];
    const float* w_ih[4]; const float* w_hh[4];
    const float* b_ih[4]; const float* b_hh[4];
    for (int l = 0; l < 4; ++l) {
        w_ih[l] = (const float*)d_in[1 + 4 * l];
        w_hh[l] = (const float*)d_in[2 + 4 * l];
        b_ih[l] = (const float*)d_in[3 + 4 * l];
        b_hh[l] = (const float*)d_in[4 + 4 * l];
    }
    const float* fc_w = (const float*)d_in[17];
    const float* fc_b = (const float*)d_in[18];
    float* out = (float*)d_out;

    char* wsb = (char*)d_ws;
    float* io  = (float*)wsb;                                   // 67,108,864 B
    float* xg  = (float*)(wsb + 67108864);                      // 33,554,432 B
    float* hst = (float*)(wsb + 67108864 + 33554432);           // 131,072 B
    float* cst = hst + BATCH * HID;                             // 131,072 B
    unsigned short* wh16 = (unsigned short*)(wsb + 67108864 + 33554432 + 262144); // 524,288 B

    // one-time f16 pack of all 4 Whh: [l][512][128]
    pack_whh<<<1024, 256, 0, stream>>>(w_hh[0], w_hh[1], w_hh[2], w_hh[3], wh16);

    dim3 ggrid(8, 256);
    for (int lyr = 0; lyr < 4; ++lyr) {
        const unsigned short* whl = wh16 + (size_t)lyr * 65536;
        for (int cchunk = 0; cchunk < TSTEPS / TC; ++cchunk) {
            int t0 = cchunk * TC;
            if (lyr == 0)
                gemm_xg<100, true><<<ggrid, 256, 0, stream>>>(x, w_ih[0], b_ih[0], b_hh[0], xg, t0);
            else
                gemm_xg<128, false><<<ggrid, 256, 0, stream>>>(io, w_ih[lyr], b_ih[lyr], b_hh[lyr], xg, t0);
            lstm_rec<<<16, 512, 0, stream>>>(xg, whl, io, hst, cst, t0, cchunk == 0 ? 1 : 0);
        }
    }
    fc_kernel<<<1, 512, 0, stream>>>(hst, fc_w, fc_b, out);
}

// Round 10
// 4274.754 us; speedup vs baseline: 1.1352x; 1.0430x over previous
//
#include <hip/hip_runtime.h>
#include <hip/hip_fp16.h>

// LSTM: 4 layers, T=512, B=256, INPUT=100, H=128, gates=512 (i,f,g,o)
// Round 9: de-bloat the MFMA scan.
//   r8 showed scan is ISSUE-bound on the 16 active CUs (per-CU VALUBusy ~72%,
//   ~2800 busy cyc/step vs ~700 declared). Suspects: (1) char*-based swizzled
//   LDS accesses -> unprovable alignment -> ds_read_b128 scalarized to u16;
//   (2) "+a" weight pins -> AGPR->VGPR copies per MFMA.
//   Fixes: typed uint4 LDS with element-index swizzle (provable 16B align);
//   pins removed (MFMA-only uses, 256-VGPR budget); rule-#18 barrier:
//   ds_write; sched_barrier; lgkmcnt(0); sched_barrier; s_barrier (no
//   "memory" clobbers, vmcnt never drained in-loop).
// ws: io 67MB | xg 33.5MB | hstate,cstate 256KB | wh16 512KB => ~101.4MB

#define TSTEPS 512
#define BATCH  256
#define HID    128
#define GATES  512
#define TC     64

typedef _Float16 half8 __attribute__((ext_vector_type(8)));
typedef float f32x4 __attribute__((ext_vector_type(4)));

__device__ __forceinline__ float sigmoid_f(float x) {
    return 1.0f / (1.0f + __expf(-x));
}
__device__ __forceinline__ float tanh_f(float x) {
    float e = __expf(2.0f * x);
    return 1.0f - 2.0f / (e + 1.0f);
}

// ---------------- Whh f16 pack: [layer][512 rows][128] row-major ----------
__global__ __launch_bounds__(256)
void pack_whh(const float* __restrict__ W0, const float* __restrict__ W1,
              const float* __restrict__ W2, const float* __restrict__ W3,
              unsigned short* __restrict__ out)
{
    int F = blockIdx.x * 256 + threadIdx.x;   // [0, 262144)
    int l = F >> 16;
    int rem = F & 65535;
    const float* W = (l == 0) ? W0 : (l == 1) ? W1 : (l == 2) ? W2 : W3;
    __half h = __float2half_rn(W[rem]);
    out[F] = __half_as_ushort(h);
}

// ---------------- input-projection GEMM (fp32, coalesced store) ----------
template<int K, bool L0>
__global__ __launch_bounds__(256, 4)
void gemm_xg(const float* __restrict__ A, const float* __restrict__ W,
             const float* __restrict__ bih, const float* __restrict__ bhh,
             float* __restrict__ XG, int t0)
{
    __shared__ float As[32][68];
    __shared__ float Bs[32][68];
    const int tid  = threadIdx.x;
    const int flat = blockIdx.y * 8 + blockIdx.x;
    const int rt   = flat & 255;
    const int ct   = flat >> 8;
    const int j0   = ct * 64;
    const int R0   = rt * 64;
    const int ty = tid >> 4, tx = tid & 15;

    float acc[4][4] = {};

    for (int kt = 0; kt < K; kt += 32) {
        #pragma unroll
        for (int i = 0; i < 8; ++i) {
            int f  = tid + 256 * i;
            int r  = f >> 5, kk = f & 31;
            int k  = kt + kk;
            int Rg = R0 + r;
            int q  = Rg >> 8, b = Rg & 255;
            float av = 0.f, wv = 0.f;
            if (K == 128 || k < K) {
                av = L0 ? A[(b * TSTEPS + (t0 + q)) * K + k]
                        : A[((t0 + q) * BATCH + b) * K + k];
                wv = W[(j0 + r) * K + k];
            }
            As[kk][r] = av;
            Bs[kk][r] = wv;
        }
        __syncthreads();
        #pragma unroll 8
        for (int kk = 0; kk < 32; ++kk) {
            float4 a4 = *(const float4*)&As[kk][ty * 4];
            float4 b4 = *(const float4*)&Bs[kk][tx * 4];
            float aa[4] = {a4.x, a4.y, a4.z, a4.w};
            float bb[4] = {b4.x, b4.y, b4.z, b4.w};
            #pragma unroll
            for (int ii = 0; ii < 4; ++ii)
                #pragma unroll
                for (int jj = 0; jj < 4; ++jj)
                    acc[ii][jj] = fmaf(aa[ii], bb[jj], acc[ii][jj]);
        }
        __syncthreads();
    }

    float4 bi = *(const float4*)&bih[j0 + tx * 4];
    float4 bh = *(const float4*)&bhh[j0 + tx * 4];
    float bsum[4] = {bi.x + bh.x, bi.y + bh.y, bi.z + bh.z, bi.w + bh.w};
    #pragma unroll
    for (int ii = 0; ii < 4; ++ii) {
        int Rg = R0 + ty * 4 + ii;
        float4 st = {acc[ii][0] + bsum[0], acc[ii][1] + bsum[1],
                     acc[ii][2] + bsum[2], acc[ii][3] + bsum[3]};
        *(float4*)&XG[(size_t)Rg * GATES + j0 + tx * 4] = st;
    }
}

// ---------------- MFMA recurrent scan ----------------
// 16 blocks x 512 thr. Block: batch rows [16*B16, +16). Wave w: units
// [16w,16w+16) x 4 gates. h^T in LDS f16 [16 rows][16 chunks of 16B],
// chunk index XOR-swizzled by (row&7). Typed uint4/uint2 accesses only.
__global__ __attribute__((amdgpu_waves_per_eu(2, 2))) __launch_bounds__(512)
void lstm_rec(const float* __restrict__ XG, const unsigned short* __restrict__ WH,
              float* __restrict__ Hout,
              float* __restrict__ hstate, float* __restrict__ cstate,
              int t0, int first)
{
    const int tid = threadIdx.x;
    const int w   = tid >> 6;
    const int l   = tid & 63;
    const int s   = l >> 4;
    const int t15 = l & 15;
    const int B16 = blockIdx.x;
    const int rb  = B16 * 16 + t15;
    const int u0  = 16 * w + 4 * s;

    __shared__ uint4 hbuf[2][256];   // [buf][row*16 + chunk], 16B chunks

    // A-frags: Whh[g*128 + 16w + t15][kt*32 + s*8 ..+8) -> 16 half8
    half8 wA[16];
    #pragma unroll
    for (int g = 0; g < 4; ++g)
        #pragma unroll
        for (int kt = 0; kt < 4; ++kt) {
            int row = g * 128 + 16 * w + t15;
            wA[g * 4 + kt] = *(const half8*)(WH + row * 128 + kt * 32 + s * 8);
        }

    float c0, c1, c2, c3, h0, h1, h2, h3;
    if (first) {
        c0 = c1 = c2 = c3 = 0.f;
        h0 = h1 = h2 = h3 = 0.f;
    } else {
        f32x4 cv = *(const f32x4*)(cstate + rb * HID + u0);
        c0 = cv[0]; c1 = cv[1]; c2 = cv[2]; c3 = cv[3];
        f32x4 hv = *(const f32x4*)(hstate + rb * HID + u0);
        h0 = hv[0]; h1 = hv[1]; h2 = hv[2]; h3 = hv[3];
    }

    // write: uint2 element index (row stride 32); chunk = 2w+(s>>1)
    const int widx = t15 * 32 + (((2 * w + (s >> 1)) ^ (t15 & 7)) << 1) + (s & 1);
    // read: uint4 element index (row stride 16); chunk = 4kt+s
    int ridx[4];
    #pragma unroll
    for (int kt = 0; kt < 4; ++kt)
        ridx[kt] = t15 * 16 + ((4 * kt + s) ^ (t15 & 7));

    {   // initial h -> hbuf[0]
        __half2 pa = __floats2half2_rn(h0, h1);
        __half2 pb = __floats2half2_rn(h2, h3);
        uint2 v = { *(unsigned int*)&pa, *(unsigned int*)&pb };
        ((uint2*)&hbuf[0][0])[widx] = v;
    }
    asm volatile("s_waitcnt lgkmcnt(0)");
    __builtin_amdgcn_sched_barrier(0);
    __builtin_amdgcn_s_barrier();
    __builtin_amdgcn_sched_barrier(0);

    // xg C-in: natural layout, float4 at (q*256+rb)*512 + g*128 + u0
    const float* xgp = XG + (size_t)rb * GATES + u0;
    f32x4 xe[4], xo[4];
    #pragma unroll
    for (int g = 0; g < 4; ++g) xe[g] = *(const f32x4*)(xgp + g * 128);
    #pragma unroll
    for (int g = 0; g < 4; ++g) xo[g] = *(const f32x4*)(xgp + 131072 + g * 128);

#define STEP(ST, RBUF, WBUF, XF)                                              \
    {                                                                         \
        half8 bf0 = __builtin_bit_cast(half8, hbuf[RBUF][ridx[0]]);           \
        half8 bf1 = __builtin_bit_cast(half8, hbuf[RBUF][ridx[1]]);           \
        half8 bf2 = __builtin_bit_cast(half8, hbuf[RBUF][ridx[2]]);           \
        half8 bf3 = __builtin_bit_cast(half8, hbuf[RBUF][ridx[3]]);           \
        f32x4 a0 = XF[0], a1 = XF[1], a2 = XF[2], a3 = XF[3];                 \
        a0 = __builtin_amdgcn_mfma_f32_16x16x32_f16(wA[0],  bf0, a0, 0, 0, 0);\
        a1 = __builtin_amdgcn_mfma_f32_16x16x32_f16(wA[4],  bf0, a1, 0, 0, 0);\
        a2 = __builtin_amdgcn_mfma_f32_16x16x32_f16(wA[8],  bf0, a2, 0, 0, 0);\
        a3 = __builtin_amdgcn_mfma_f32_16x16x32_f16(wA[12], bf0, a3, 0, 0, 0);\
        a0 = __builtin_amdgcn_mfma_f32_16x16x32_f16(wA[1],  bf1, a0, 0, 0, 0);\
        a1 = __builtin_amdgcn_mfma_f32_16x16x32_f16(wA[5],  bf1, a1, 0, 0, 0);\
        a2 = __builtin_amdgcn_mfma_f32_16x16x32_f16(wA[9],  bf1, a2, 0, 0, 0);\
        a3 = __builtin_amdgcn_mfma_f32_16x16x32_f16(wA[13], bf1, a3, 0, 0, 0);\
        a0 = __builtin_amdgcn_mfma_f32_16x16x32_f16(wA[2],  bf2, a0, 0, 0, 0);\
        a1 = __builtin_amdgcn_mfma_f32_16x16x32_f16(wA[6],  bf2, a1, 0, 0, 0);\
        a2 = __builtin_amdgcn_mfma_f32_16x16x32_f16(wA[10], bf2, a2, 0, 0, 0);\
        a3 = __builtin_amdgcn_mfma_f32_16x16x32_f16(wA[14], bf2, a3, 0, 0, 0);\
        a0 = __builtin_amdgcn_mfma_f32_16x16x32_f16(wA[3],  bf3, a0, 0, 0, 0);\
        a1 = __builtin_amdgcn_mfma_f32_16x16x32_f16(wA[7],  bf3, a1, 0, 0, 0);\
        a2 = __builtin_amdgcn_mfma_f32_16x16x32_f16(wA[11], bf3, a2, 0, 0, 0);\
        a3 = __builtin_amdgcn_mfma_f32_16x16x32_f16(wA[15], bf3, a3, 0, 0, 0);\
        if ((ST) + 2 < TC) {                                                  \
            const float* xp = xgp + (size_t)((ST) + 2) * 131072;              \
            XF[0] = *(const f32x4*)(xp);                                      \
            XF[1] = *(const f32x4*)(xp + 128);                                \
            XF[2] = *(const f32x4*)(xp + 256);                                \
            XF[3] = *(const f32x4*)(xp + 384);                                \
        }                                                                     \
        c0 = sigmoid_f(a1[0]) * c0 + sigmoid_f(a0[0]) * tanh_f(a2[0]);        \
        h0 = sigmoid_f(a3[0]) * tanh_f(c0);                                   \
        c1 = sigmoid_f(a1[1]) * c1 + sigmoid_f(a0[1]) * tanh_f(a2[1]);        \
        h1 = sigmoid_f(a3[1]) * tanh_f(c1);                                   \
        c2 = sigmoid_f(a1[2]) * c2 + sigmoid_f(a0[2]) * tanh_f(a2[2]);        \
        h2 = sigmoid_f(a3[2]) * tanh_f(c2);                                   \
        c3 = sigmoid_f(a1[3]) * c3 + sigmoid_f(a0[3]) * tanh_f(a2[3]);        \
        h3 = sigmoid_f(a3[3]) * tanh_f(c3);                                   \
        {                                                                     \
            __half2 pa = __floats2half2_rn(h0, h1);                           \
            __half2 pb = __floats2half2_rn(h2, h3);                           \
            uint2 v = { *(unsigned int*)&pa, *(unsigned int*)&pb };           \
            ((uint2*)&hbuf[WBUF][0])[widx] = v;                               \
        }                                                                     \
        f32x4 hv = {h0, h1, h2, h3};                                          \
        *(f32x4*)(Hout + ((size_t)(t0 + (ST)) * BATCH + rb) * HID + u0) = hv; \
        __builtin_amdgcn_sched_barrier(0);                                    \
        asm volatile("s_waitcnt lgkmcnt(0)");                                 \
        __builtin_amdgcn_sched_barrier(0);                                    \
        __builtin_amdgcn_s_barrier();                                         \
        __builtin_amdgcn_sched_barrier(0);                                    \
    }

    for (int st = 0; st < TC; st += 2) {
        STEP(st,     0, 1, xe);
        STEP(st + 1, 1, 0, xo);
    }
#undef STEP

    f32x4 cv = {c0, c1, c2, c3};
    f32x4 hv = {h0, h1, h2, h3};
    *(f32x4*)(cstate + rb * HID + u0) = cv;
    *(f32x4*)(hstate + rb * HID + u0) = hv;
}

// ---------------- final FC ----------------
__global__ __launch_bounds__(512)
void fc_kernel(const float* __restrict__ hstate, const float* __restrict__ fcw,
               const float* __restrict__ fcb, float* __restrict__ out)
{
    int idx = threadIdx.x;      // 512 = 256 rows x 2 outs
    int b = idx >> 1, o = idx & 1;
    float acc = fcb[o];
    #pragma unroll
    for (int k = 0; k < HID; ++k)
        acc = fmaf(hstate[b * HID + k], fcw[o * HID + k], acc);
    out[b * 2 + o] = acc;
}

extern "C" void kernel_launch(void* const* d_in, const int* in_sizes, int n_in,
                              void* d_out, int out_size, void* d_ws, size_t ws_size,
                              hipStream_t stream)
{
    const float* x = (const float*)d_in[0];
    const float* w_ih[4]; const float* w_hh[4];
    const float* b_ih[4]; const float* b_hh[4];
    for (int l = 0; l < 4; ++l) {
        w_ih[l] = (const float*)d_in[1 + 4 * l];
        w_hh[l] = (const float*)d_in[2 + 4 * l];
        b_ih[l] = (const float*)d_in[3 + 4 * l];
        b_hh[l] = (const float*)d_in[4 + 4 * l];
    }
    const float* fc_w = (const float*)d_in[17];
    const float* fc_b = (const float*)d_in[18];
    float* out = (float*)d_out;

    char* wsb = (char*)d_ws;
    float* io  = (float*)wsb;                                   // 67,108,864 B
    float* xg  = (float*)(wsb + 67108864);                      // 33,554,432 B
    float* hst = (float*)(wsb + 67108864 + 33554432);           // 131,072 B
    float* cst = hst + BATCH * HID;                             // 131,072 B
    unsigned short* wh16 = (unsigned short*)(wsb + 67108864 + 33554432 + 262144); // 524,288 B

    // one-time f16 pack of all 4 Whh: [l][512][128]
    pack_whh<<<1024, 256, 0, stream>>>(w_hh[0], w_hh[1], w_hh[2], w_hh[3], wh16);

    dim3 ggrid(8, 256);
    for (int lyr = 0; lyr < 4; ++lyr) {
        const unsigned short* whl = wh16 + (size_t)lyr * 65536;
        for (int cchunk = 0; cchunk < TSTEPS / TC; ++cchunk) {
            int t0 = cchunk * TC;
            if (lyr == 0)
                gemm_xg<100, true><<<ggrid, 256, 0, stream>>>(x, w_ih[0], b_ih[0], b_hh[0], xg, t0);
            else
                gemm_xg<128, false><<<ggrid, 256, 0, stream>>>(io, w_ih[lyr], b_ih[lyr], b_hh[lyr], xg, t0);
            lstm_rec<<<16, 512, 0, stream>>>(xg, whl, io, hst, cst, t0, cchunk == 0 ? 1 : 0);
        }
    }
    fc_kernel<<<1, 512, 0, stream>>>(hst, fc_w, fc_b, out);
}

// Round 11
// 3040.106 us; speedup vs baseline: 1.5962x; 1.4061x over previous
//
#include <hip/hip_runtime.h>
#include <hip/hip_fp16.h>

// LSTM: 4 layers, T=512, B=256, INPUT=100, H=128, gates=512 (i,f,g,o)
// Round 10:
//  - r9 post-mortem: scan is ACTIVATION-issue-bound: 20 sigmoid/tanh per
//    thread/step, each with a no-fast-math IEEE fp32 division (~10 ops) ->
//    ~260 VALU insts/thread/step. Fix: native v_rcp via
//    __builtin_amdgcn_rcpf (exp already native __expf). ~2.4x fewer insts.
//  - gemm: fp32 VALU gemm (~30us x32) -> f16 MFMA gemm (~8us): uniform
//    K=128 (zero-padded packed w_ih; per-chunk packed x tile), no LDS,
//    frags from global (W L2-hot), bias as C-init. xg layout unchanged.
//  - scan writes f16 hio (pre-packed half2s) -> feeds next layer's gemm.
// ws: hio 33.5MB | xg 33.5MB | xc16 4MB | hst/cst 256KB | wih16/whh16 1MB
//     => ~69.3MB total.

#define TSTEPS 512
#define BATCH  256
#define HID    128
#define GATES  512
#define TC     64

typedef _Float16 half8 __attribute__((ext_vector_type(8)));
typedef float f32x4 __attribute__((ext_vector_type(4)));

// native-rate activations: 2 full + 2 trans ops each (no IEEE div sequence)
__device__ __forceinline__ float sigmoid_f(float x) {
    return __builtin_amdgcn_rcpf(1.0f + __expf(-x));
}
__device__ __forceinline__ float tanh_f(float x) {
    float e = __expf(2.0f * x);
    return 1.0f - 2.0f * __builtin_amdgcn_rcpf(e + 1.0f);
}

// ---------------- packs ----------------
// Whh f16: [layer][512 rows][128] row-major
__global__ __launch_bounds__(256)
void pack_whh(const float* __restrict__ W0, const float* __restrict__ W1,
              const float* __restrict__ W2, const float* __restrict__ W3,
              unsigned short* __restrict__ out)
{
    int F = blockIdx.x * 256 + threadIdx.x;   // [0, 262144)
    int l = F >> 16;
    int rem = F & 65535;
    const float* W = (l == 0) ? W0 : (l == 1) ? W1 : (l == 2) ? W2 : W3;
    out[F] = __half_as_ushort(__float2half_rn(W[rem]));
}

// w_ih f16, zero-padded to K=128: [layer][512][128]
__global__ __launch_bounds__(256)
void pack_wih(const float* __restrict__ W0, const float* __restrict__ W1,
              const float* __restrict__ W2, const float* __restrict__ W3,
              unsigned short* __restrict__ out)
{
    int F = blockIdx.x * 256 + threadIdx.x;   // [0, 262144)
    int l = F >> 16;
    int rem = F & 65535;
    int row = rem >> 7, kk = rem & 127;
    float v;
    if (l == 0) {
        v = (kk < 100) ? W0[row * 100 + kk] : 0.f;
    } else {
        const float* W = (l == 1) ? W1 : (l == 2) ? W2 : W3;
        v = W[row * 128 + kk];
    }
    out[F] = __half_as_ushort(__float2half_rn(v));
}

// x chunk pack: x[b][t0+q][k<100] f32 -> xc16[q][b][128] f16 (zero-pad)
__global__ __launch_bounds__(256)
void pack_xc(const float* __restrict__ X, unsigned int* __restrict__ out, int t0)
{
    int F = blockIdx.x * 256 + threadIdx.x;   // [0, 1048576) pairs
    int kp = F & 63;
    int row = F >> 6;                          // q*256 + b
    int q = row >> 8, b = row & 255;
    const float* src = X + ((size_t)b * TSTEPS + (t0 + q)) * 100 + kp * 2;
    float v0 = (kp * 2     < 100) ? src[0] : 0.f;
    float v1 = (kp * 2 + 1 < 100) ? src[1] : 0.f;
    __half2 hh = __floats2half2_rn(v0, v1);
    out[F] = *(unsigned int*)&hh;
}

// ---------------- f16 MFMA input-projection GEMM ----------------
// XG[row, j] = A[row,:]·W[j,:] + b_ih[j] + b_hh[j]; rows = q*256+b (16384),
// j in [0,512), K=128. Block 512 thr = 8 waves; wave = 16 rows x 64 cols
// (4 16x16 tiles, K-loop 4). Frags direct from global; bias = C-init.
__global__ __launch_bounds__(512)
void gemm_xg16(const unsigned short* __restrict__ AIN,
               const unsigned short* __restrict__ WG,
               const float* __restrict__ bih, const float* __restrict__ bhh,
               float* __restrict__ XG, int rowoff)
{
    const int tid = threadIdx.x;
    const int w = tid >> 6, l = tid & 63, s = l >> 4, t15 = l & 15;
    const int R0 = blockIdx.y * 128 + w * 16;   // chunk-local row base
    const int C0 = blockIdx.x * 64;
    const unsigned short* arow = AIN + ((size_t)(rowoff + R0 + t15)) * 128 + s * 8;

    f32x4 acc[4];
    #pragma unroll
    for (int jt = 0; jt < 4; ++jt) {
        int j = C0 + jt * 16 + t15;
        float bs = bih[j] + bhh[j];
        acc[jt] = (f32x4){bs, bs, bs, bs};
    }
    #pragma unroll
    for (int kt = 0; kt < 4; ++kt) {
        half8 af = *(const half8*)(arow + kt * 32);
        #pragma unroll
        for (int jt = 0; jt < 4; ++jt) {
            half8 bf = *(const half8*)(WG + (size_t)(C0 + jt * 16 + t15) * 128 + kt * 32 + s * 8);
            acc[jt] = __builtin_amdgcn_mfma_f32_16x16x32_f16(af, bf, acc[jt], 0, 0, 0);
        }
    }
    #pragma unroll
    for (int jt = 0; jt < 4; ++jt) {
        int j = C0 + jt * 16 + t15;
        #pragma unroll
        for (int r = 0; r < 4; ++r)
            XG[(size_t)(R0 + s * 4 + r) * GATES + j] = acc[jt][r];
    }
}

// ---------------- MFMA recurrent scan ----------------
// 16 blocks x 512 thr. Block: batch rows [16*B16,+16). Wave w: units
// [16w,16w+16) x 4 gates. h^T LDS f16, chunk-XOR swizzle, typed uint4.
__global__ __attribute__((amdgpu_waves_per_eu(2, 2))) __launch_bounds__(512)
void lstm_rec(const float* __restrict__ XG, const unsigned short* __restrict__ WH,
              unsigned short* __restrict__ HIO,
              float* __restrict__ hstate, float* __restrict__ cstate,
              int t0, int first)
{
    const int tid = threadIdx.x;
    const int w   = tid >> 6;
    const int l   = tid & 63;
    const int s   = l >> 4;
    const int t15 = l & 15;
    const int B16 = blockIdx.x;
    const int rb  = B16 * 16 + t15;
    const int u0  = 16 * w + 4 * s;

    __shared__ uint4 hbuf[2][256];   // [buf][row*16 + chunk], 16B chunks

    half8 wA[16];
    #pragma unroll
    for (int g = 0; g < 4; ++g)
        #pragma unroll
        for (int kt = 0; kt < 4; ++kt) {
            int row = g * 128 + 16 * w + t15;
            wA[g * 4 + kt] = *(const half8*)(WH + row * 128 + kt * 32 + s * 8);
        }

    float c0, c1, c2, c3, h0, h1, h2, h3;
    if (first) {
        c0 = c1 = c2 = c3 = 0.f;
        h0 = h1 = h2 = h3 = 0.f;
    } else {
        f32x4 cv = *(const f32x4*)(cstate + rb * HID + u0);
        c0 = cv[0]; c1 = cv[1]; c2 = cv[2]; c3 = cv[3];
        f32x4 hv = *(const f32x4*)(hstate + rb * HID + u0);
        h0 = hv[0]; h1 = hv[1]; h2 = hv[2]; h3 = hv[3];
    }

    const int widx = t15 * 32 + (((2 * w + (s >> 1)) ^ (t15 & 7)) << 1) + (s & 1);
    int ridx[4];
    #pragma unroll
    for (int kt = 0; kt < 4; ++kt)
        ridx[kt] = t15 * 16 + ((4 * kt + s) ^ (t15 & 7));

    {   // initial h -> hbuf[0]
        __half2 pa = __floats2half2_rn(h0, h1);
        __half2 pb = __floats2half2_rn(h2, h3);
        uint2 v = { *(unsigned int*)&pa, *(unsigned int*)&pb };
        ((uint2*)&hbuf[0][0])[widx] = v;
    }
    asm volatile("s_waitcnt lgkmcnt(0)");
    __builtin_amdgcn_sched_barrier(0);
    __builtin_amdgcn_s_barrier();
    __builtin_amdgcn_sched_barrier(0);

    const float* xgp = XG + (size_t)rb * GATES + u0;
    f32x4 xe[4], xo[4];
    #pragma unroll
    for (int g = 0; g < 4; ++g) xe[g] = *(const f32x4*)(xgp + g * 128);
    #pragma unroll
    for (int g = 0; g < 4; ++g) xo[g] = *(const f32x4*)(xgp + 131072 + g * 128);

#define STEP(ST, RBUF, WBUF, XF)                                              \
    {                                                                         \
        half8 bf0 = __builtin_bit_cast(half8, hbuf[RBUF][ridx[0]]);           \
        half8 bf1 = __builtin_bit_cast(half8, hbuf[RBUF][ridx[1]]);           \
        half8 bf2 = __builtin_bit_cast(half8, hbuf[RBUF][ridx[2]]);           \
        half8 bf3 = __builtin_bit_cast(half8, hbuf[RBUF][ridx[3]]);           \
        f32x4 a0 = XF[0], a1 = XF[1], a2 = XF[2], a3 = XF[3];                 \
        a0 = __builtin_amdgcn_mfma_f32_16x16x32_f16(wA[0],  bf0, a0, 0, 0, 0);\
        a1 = __builtin_amdgcn_mfma_f32_16x16x32_f16(wA[4],  bf0, a1, 0, 0, 0);\
        a2 = __builtin_amdgcn_mfma_f32_16x16x32_f16(wA[8],  bf0, a2, 0, 0, 0);\
        a3 = __builtin_amdgcn_mfma_f32_16x16x32_f16(wA[12], bf0, a3, 0, 0, 0);\
        a0 = __builtin_amdgcn_mfma_f32_16x16x32_f16(wA[1],  bf1, a0, 0, 0, 0);\
        a1 = __builtin_amdgcn_mfma_f32_16x16x32_f16(wA[5],  bf1, a1, 0, 0, 0);\
        a2 = __builtin_amdgcn_mfma_f32_16x16x32_f16(wA[9],  bf1, a2, 0, 0, 0);\
        a3 = __builtin_amdgcn_mfma_f32_16x16x32_f16(wA[13], bf1, a3, 0, 0, 0);\
        a0 = __builtin_amdgcn_mfma_f32_16x16x32_f16(wA[2],  bf2, a0, 0, 0, 0);\
        a1 = __builtin_amdgcn_mfma_f32_16x16x32_f16(wA[6],  bf2, a1, 0, 0, 0);\
        a2 = __builtin_amdgcn_mfma_f32_16x16x32_f16(wA[10], bf2, a2, 0, 0, 0);\
        a3 = __builtin_amdgcn_mfma_f32_16x16x32_f16(wA[14], bf2, a3, 0, 0, 0);\
        a0 = __builtin_amdgcn_mfma_f32_16x16x32_f16(wA[3],  bf3, a0, 0, 0, 0);\
        a1 = __builtin_amdgcn_mfma_f32_16x16x32_f16(wA[7],  bf3, a1, 0, 0, 0);\
        a2 = __builtin_amdgcn_mfma_f32_16x16x32_f16(wA[11], bf3, a2, 0, 0, 0);\
        a3 = __builtin_amdgcn_mfma_f32_16x16x32_f16(wA[15], bf3, a3, 0, 0, 0);\
        if ((ST) + 2 < TC) {                                                  \
            const float* xp = xgp + (size_t)((ST) + 2) * 131072;              \
            XF[0] = *(const f32x4*)(xp);                                      \
            XF[1] = *(const f32x4*)(xp + 128);                                \
            XF[2] = *(const f32x4*)(xp + 256);                                \
            XF[3] = *(const f32x4*)(xp + 384);                                \
        }                                                                     \
        c0 = sigmoid_f(a1[0]) * c0 + sigmoid_f(a0[0]) * tanh_f(a2[0]);        \
        h0 = sigmoid_f(a3[0]) * tanh_f(c0);                                   \
        c1 = sigmoid_f(a1[1]) * c1 + sigmoid_f(a0[1]) * tanh_f(a2[1]);        \
        h1 = sigmoid_f(a3[1]) * tanh_f(c1);                                   \
        c2 = sigmoid_f(a1[2]) * c2 + sigmoid_f(a0[2]) * tanh_f(a2[2]);        \
        h2 = sigmoid_f(a3[2]) * tanh_f(c2);                                   \
        c3 = sigmoid_f(a1[3]) * c3 + sigmoid_f(a0[3]) * tanh_f(a2[3]);        \
        h3 = sigmoid_f(a3[3]) * tanh_f(c3);                                   \
        {                                                                     \
            __half2 pa = __floats2half2_rn(h0, h1);                           \
            __half2 pb = __floats2half2_rn(h2, h3);                           \
            uint2 v = { *(unsigned int*)&pa, *(unsigned int*)&pb };           \
            ((uint2*)&hbuf[WBUF][0])[widx] = v;                               \
            *(uint2*)(HIO + ((size_t)(t0 + (ST)) * BATCH + rb) * HID + u0) = v;\
        }                                                                     \
        __builtin_amdgcn_sched_barrier(0);                                    \
        asm volatile("s_waitcnt lgkmcnt(0)");                                 \
        __builtin_amdgcn_sched_barrier(0);                                    \
        __builtin_amdgcn_s_barrier();                                         \
        __builtin_amdgcn_sched_barrier(0);                                    \
    }

    for (int st = 0; st < TC; st += 2) {
        STEP(st,     0, 1, xe);
        STEP(st + 1, 1, 0, xo);
    }
#undef STEP

    f32x4 cv = {c0, c1, c2, c3};
    f32x4 hv = {h0, h1, h2, h3};
    *(f32x4*)(cstate + rb * HID + u0) = cv;
    *(f32x4*)(hstate + rb * HID + u0) = hv;
}

// ---------------- final FC ----------------
__global__ __launch_bounds__(512)
void fc_kernel(const float* __restrict__ hstate, const float* __restrict__ fcw,
               const float* __restrict__ fcb, float* __restrict__ out)
{
    int idx = threadIdx.x;      // 512 = 256 rows x 2 outs
    int b = idx >> 1, o = idx & 1;
    float acc = fcb[o];
    #pragma unroll
    for (int k = 0; k < HID; ++k)
        acc = fmaf(hstate[b * HID + k], fcw[o * HID + k], acc);
    out[b * 2 + o] = acc;
}

extern "C" void kernel_launch(void* const* d_in, const int* in_sizes, int n_in,
                              void* d_out, int out_size, void* d_ws, size_t ws_size,
                              hipStream_t stream)
{
    const float* x = (const float*)d_in[0];
    const float* w_ih[4]; const float* w_hh[4];
    const float* b_ih[4]; const float* b_hh[4];
    for (int l = 0; l < 4; ++l) {
        w_ih[l] = (const float*)d_in[1 + 4 * l];
        w_hh[l] = (const float*)d_in[2 + 4 * l];
        b_ih[l] = (const float*)d_in[3 + 4 * l];
        b_hh[l] = (const float*)d_in[4 + 4 * l];
    }
    const float* fc_w = (const float*)d_in[17];
    const float* fc_b = (const float*)d_in[18];
    float* out = (float*)d_out;

    char* wsb = (char*)d_ws;
    unsigned short* hio  = (unsigned short*)wsb;                    // 33,554,432 B
    float*          xg   = (float*)(wsb + 33554432);                // 33,554,432 B
    unsigned short* xc16 = (unsigned short*)(wsb + 67108864);       //  4,194,304 B
    float*          hst  = (float*)(wsb + 71303168);                //    131,072 B
    float*          cst  = (float*)(wsb + 71434240);                //    131,072 B
    unsigned short* wih16 = (unsigned short*)(wsb + 71565312);      //    524,288 B
    unsigned short* whh16 = (unsigned short*)(wsb + 72089600);      //    524,288 B

    pack_whh<<<1024, 256, 0, stream>>>(w_hh[0], w_hh[1], w_hh[2], w_hh[3], whh16);
    pack_wih<<<1024, 256, 0, stream>>>(w_ih[0], w_ih[1], w_ih[2], w_ih[3], wih16);

    dim3 ggrid(8, 128);   // x = 64-col tile, y = 128-row tile
    for (int lyr = 0; lyr < 4; ++lyr) {
        const unsigned short* whl = whh16 + (size_t)lyr * 65536;
        const unsigned short* wil = wih16 + (size_t)lyr * 65536;
        for (int cchunk = 0; cchunk < TSTEPS / TC; ++cchunk) {
            int t0 = cchunk * TC;
            if (lyr == 0) {
                pack_xc<<<4096, 256, 0, stream>>>(x, (unsigned int*)xc16, t0);
                gemm_xg16<<<ggrid, 512, 0, stream>>>(xc16, wil, b_ih[0], b_hh[0], xg, 0);
            } else {
                gemm_xg16<<<ggrid, 512, 0, stream>>>(hio, wil, b_ih[lyr], b_hh[lyr], xg, t0 * BATCH);
            }
            lstm_rec<<<16, 512, 0, stream>>>(xg, whl, hio, hst, cst, t0, cchunk == 0 ? 1 : 0);
        }
    }
    fc_kernel<<<1, 512, 0, stream>>>(hst, fc_w, fc_b, out);
}

// Round 12
// 2324.872 us; speedup vs baseline: 2.0872x; 1.3076x over previous
//
#include <hip/hip_runtime.h>
#include <hip/hip_fp16.h>

// LSTM: 4 layers, T=512, B=256, INPUT=100, H=128, gates=512 (i,f,g,o)
// Round 11: fuse gemm(chunk c+1) into scan(chunk c)'s kernel.
//   r10 left: 32 x 71.6us scan on 16 CUs + ~750us of serialized gemm/pack
//   on the other 240 idle CUs. gemm(l,c+1) depends only on layer l-1 hio
//   (done >=1 kernel earlier), NOT on scan(l,c) -> same-kernel disjoint
//   blocks: 0-15 scan (reads xg[i&1]), 16-143 gemm -> xg[(i+1)&1].
//   L0 gemm converts f32 x inline (predicated k<100) -> pack_xc gone.
//   Scan internals identical to r10 (validated: 71.6us, absmax 4.9e-4).
// ws: hio 33.5MB | xgA 33.5MB | xgB 33.5MB | hst/cst 256KB | wih/whh 1MB
//     => ~97.4MB (round-0 proved ~101MB safe).

#define TSTEPS 512
#define BATCH  256
#define HID    128
#define GATES  512
#define TC     64

typedef _Float16 half8 __attribute__((ext_vector_type(8)));
typedef float f32x4 __attribute__((ext_vector_type(4)));

__device__ __forceinline__ float sigmoid_f(float x) {
    return __builtin_amdgcn_rcpf(1.0f + __expf(-x));
}
__device__ __forceinline__ float tanh_f(float x) {
    float e = __expf(2.0f * x);
    return 1.0f - 2.0f * __builtin_amdgcn_rcpf(e + 1.0f);
}

// ---------------- packs ----------------
__global__ __launch_bounds__(256)
void pack_whh(const float* __restrict__ W0, const float* __restrict__ W1,
              const float* __restrict__ W2, const float* __restrict__ W3,
              unsigned short* __restrict__ out)
{
    int F = blockIdx.x * 256 + threadIdx.x;   // [0, 262144)
    int l = F >> 16;
    int rem = F & 65535;
    const float* W = (l == 0) ? W0 : (l == 1) ? W1 : (l == 2) ? W2 : W3;
    out[F] = __half_as_ushort(__float2half_rn(W[rem]));
}

__global__ __launch_bounds__(256)
void pack_wih(const float* __restrict__ W0, const float* __restrict__ W1,
              const float* __restrict__ W2, const float* __restrict__ W3,
              unsigned short* __restrict__ out)
{
    int F = blockIdx.x * 256 + threadIdx.x;   // [0, 262144)
    int l = F >> 16;
    int rem = F & 65535;
    int row = rem >> 7, kk = rem & 127;
    float v;
    if (l == 0) {
        v = (kk < 100) ? W0[row * 100 + kk] : 0.f;
    } else {
        const float* W = (l == 1) ? W1 : (l == 2) ? W2 : W3;
        v = W[row * 128 + kk];
    }
    out[F] = __half_as_ushort(__float2half_rn(v));
}

// ---------------- gemm device path ----------------
// Computes 128 rows of XG[row, 0..512) for one chunk. gb in [0,128).
// mode 1: A from f32 x (zero-pad k>=100), t0n = chunk t0.
// mode 2: A from f16 hio, rowoff = t0n*256.
__device__ __forceinline__ void gemm_path(
    int gb, int tid, int mode,
    const float* __restrict__ X, const unsigned short* __restrict__ HIO,
    int rowoff, int t0n,
    const unsigned short* __restrict__ WG,
    const float* __restrict__ bih, const float* __restrict__ bhh,
    float* __restrict__ XGW)
{
    const int w = tid >> 6, l = tid & 63, s = l >> 4, t15 = l & 15;
    const int r = gb * 128 + w * 16 + t15;   // chunk-local row, [0,16384)

    half8 af[4];
    if (mode == 1) {
        int q = r >> 8, b = r & 255;
        const float* src = X + ((size_t)b * TSTEPS + (t0n + q)) * 100;
        #pragma unroll
        for (int kt = 0; kt < 4; ++kt) {
            half8 h;
            #pragma unroll
            for (int e = 0; e < 8; ++e) {
                int k = kt * 32 + s * 8 + e;
                float v = (k < 100) ? src[k] : 0.f;
                h[e] = (_Float16)v;
            }
            af[kt] = h;
        }
    } else {
        const unsigned short* arow = HIO + ((size_t)(rowoff + r)) * 128 + s * 8;
        #pragma unroll
        for (int kt = 0; kt < 4; ++kt)
            af[kt] = *(const half8*)(arow + kt * 32);
    }

    #pragma unroll 1
    for (int cg = 0; cg < 4; ++cg) {       // 4 col groups of 128
        f32x4 acc[8];
        #pragma unroll
        for (int jt = 0; jt < 8; ++jt) {
            int j = cg * 128 + jt * 16 + t15;
            float bs = bih[j] + bhh[j];
            acc[jt] = (f32x4){bs, bs, bs, bs};
        }
        #pragma unroll
        for (int kt = 0; kt < 4; ++kt) {
            #pragma unroll
            for (int jt = 0; jt < 8; ++jt) {
                half8 bf = *(const half8*)(WG + (size_t)(cg * 128 + jt * 16 + t15) * 128 + kt * 32 + s * 8);
                acc[jt] = __builtin_amdgcn_mfma_f32_16x16x32_f16(af[kt], bf, acc[jt], 0, 0, 0);
            }
        }
        const int rr = gb * 128 + w * 16 + s * 4;
        #pragma unroll
        for (int jt = 0; jt < 8; ++jt) {
            int j = cg * 128 + jt * 16 + t15;
            #pragma unroll
            for (int rg = 0; rg < 4; ++rg)
                XGW[(size_t)(rr + rg) * GATES + j] = acc[jt][rg];
        }
    }
}

// ---------------- fused: scan(chunk c) + gemm(chunk c+1) ----------------
// blocks 0..15: MFMA recurrent scan (r10 structure, unchanged).
// blocks 16..143: gemm_path into the other xg buffer (if gmode != 0).
__global__ __attribute__((amdgpu_waves_per_eu(2, 2))) __launch_bounds__(512)
void fused_step(const float* __restrict__ XGR, float* __restrict__ XGW,
                const unsigned short* __restrict__ WH,
                unsigned short* __restrict__ HIO,
                float* __restrict__ hstate, float* __restrict__ cstate,
                int t0, int first,
                int gmode, const float* __restrict__ X, int growoff, int gt0,
                const unsigned short* __restrict__ WG,
                const float* __restrict__ gbih, const float* __restrict__ gbhh)
{
    __shared__ uint4 hbuf[2][256];   // scan h^T double buffer (16B chunks)

    if (blockIdx.x >= 16) {
        if (gmode)
            gemm_path(blockIdx.x - 16, threadIdx.x, gmode, X, HIO, growoff,
                      gt0, WG, gbih, gbhh, XGW);
        return;
    }

    // ---- scan path ----
    const int tid = threadIdx.x;
    const int w   = tid >> 6;
    const int l   = tid & 63;
    const int s   = l >> 4;
    const int t15 = l & 15;
    const int B16 = blockIdx.x;
    const int rb  = B16 * 16 + t15;
    const int u0  = 16 * w + 4 * s;

    half8 wA[16];
    #pragma unroll
    for (int g = 0; g < 4; ++g)
        #pragma unroll
        for (int kt = 0; kt < 4; ++kt) {
            int row = g * 128 + 16 * w + t15;
            wA[g * 4 + kt] = *(const half8*)(WH + row * 128 + kt * 32 + s * 8);
        }

    float c0, c1, c2, c3, h0, h1, h2, h3;
    if (first) {
        c0 = c1 = c2 = c3 = 0.f;
        h0 = h1 = h2 = h3 = 0.f;
    } else {
        f32x4 cv = *(const f32x4*)(cstate + rb * HID + u0);
        c0 = cv[0]; c1 = cv[1]; c2 = cv[2]; c3 = cv[3];
        f32x4 hv = *(const f32x4*)(hstate + rb * HID + u0);
        h0 = hv[0]; h1 = hv[1]; h2 = hv[2]; h3 = hv[3];
    }

    const int widx = t15 * 32 + (((2 * w + (s >> 1)) ^ (t15 & 7)) << 1) + (s & 1);
    int ridx[4];
    #pragma unroll
    for (int kt = 0; kt < 4; ++kt)
        ridx[kt] = t15 * 16 + ((4 * kt + s) ^ (t15 & 7));

    {   // initial h -> hbuf[0]
        __half2 pa = __floats2half2_rn(h0, h1);
        __half2 pb = __floats2half2_rn(h2, h3);
        uint2 v = { *(unsigned int*)&pa, *(unsigned int*)&pb };
        ((uint2*)&hbuf[0][0])[widx] = v;
    }
    asm volatile("s_waitcnt lgkmcnt(0)");
    __builtin_amdgcn_sched_barrier(0);
    __builtin_amdgcn_s_barrier();
    __builtin_amdgcn_sched_barrier(0);

    const float* xgp = XGR + (size_t)rb * GATES + u0;
    f32x4 xe[4], xo[4];
    #pragma unroll
    for (int g = 0; g < 4; ++g) xe[g] = *(const f32x4*)(xgp + g * 128);
    #pragma unroll
    for (int g = 0; g < 4; ++g) xo[g] = *(const f32x4*)(xgp + 131072 + g * 128);

#define STEP(ST, RBUF, WBUF, XF)                                              \
    {                                                                         \
        half8 bf0 = __builtin_bit_cast(half8, hbuf[RBUF][ridx[0]]);           \
        half8 bf1 = __builtin_bit_cast(half8, hbuf[RBUF][ridx[1]]);           \
        half8 bf2 = __builtin_bit_cast(half8, hbuf[RBUF][ridx[2]]);           \
        half8 bf3 = __builtin_bit_cast(half8, hbuf[RBUF][ridx[3]]);           \
        f32x4 a0 = XF[0], a1 = XF[1], a2 = XF[2], a3 = XF[3];                 \
        a0 = __builtin_amdgcn_mfma_f32_16x16x32_f16(wA[0],  bf0, a0, 0, 0, 0);\
        a1 = __builtin_amdgcn_mfma_f32_16x16x32_f16(wA[4],  bf0, a1, 0, 0, 0);\
        a2 = __builtin_amdgcn_mfma_f32_16x16x32_f16(wA[8],  bf0, a2, 0, 0, 0);\
        a3 = __builtin_amdgcn_mfma_f32_16x16x32_f16(wA[12], bf0, a3, 0, 0, 0);\
        a0 = __builtin_amdgcn_mfma_f32_16x16x32_f16(wA[1],  bf1, a0, 0, 0, 0);\
        a1 = __builtin_amdgcn_mfma_f32_16x16x32_f16(wA[5],  bf1, a1, 0, 0, 0);\
        a2 = __builtin_amdgcn_mfma_f32_16x16x32_f16(wA[9],  bf1, a2, 0, 0, 0);\
        a3 = __builtin_amdgcn_mfma_f32_16x16x32_f16(wA[13], bf1, a3, 0, 0, 0);\
        a0 = __builtin_amdgcn_mfma_f32_16x16x32_f16(wA[2],  bf2, a0, 0, 0, 0);\
        a1 = __builtin_amdgcn_mfma_f32_16x16x32_f16(wA[6],  bf2, a1, 0, 0, 0);\
        a2 = __builtin_amdgcn_mfma_f32_16x16x32_f16(wA[10], bf2, a2, 0, 0, 0);\
        a3 = __builtin_amdgcn_mfma_f32_16x16x32_f16(wA[14], bf2, a3, 0, 0, 0);\
        a0 = __builtin_amdgcn_mfma_f32_16x16x32_f16(wA[3],  bf3, a0, 0, 0, 0);\
        a1 = __builtin_amdgcn_mfma_f32_16x16x32_f16(wA[7],  bf3, a1, 0, 0, 0);\
        a2 = __builtin_amdgcn_mfma_f32_16x16x32_f16(wA[11], bf3, a2, 0, 0, 0);\
        a3 = __builtin_amdgcn_mfma_f32_16x16x32_f16(wA[15], bf3, a3, 0, 0, 0);\
        if ((ST) + 2 < TC) {                                                  \
            const float* xp = xgp + (size_t)((ST) + 2) * 131072;              \
            XF[0] = *(const f32x4*)(xp);                                      \
            XF[1] = *(const f32x4*)(xp + 128);                                \
            XF[2] = *(const f32x4*)(xp + 256);                                \
            XF[3] = *(const f32x4*)(xp + 384);                                \
        }                                                                     \
        c0 = sigmoid_f(a1[0]) * c0 + sigmoid_f(a0[0]) * tanh_f(a2[0]);        \
        h0 = sigmoid_f(a3[0]) * tanh_f(c0);                                   \
        c1 = sigmoid_f(a1[1]) * c1 + sigmoid_f(a0[1]) * tanh_f(a2[1]);        \
        h1 = sigmoid_f(a3[1]) * tanh_f(c1);                                   \
        c2 = sigmoid_f(a1[2]) * c2 + sigmoid_f(a0[2]) * tanh_f(a2[2]);        \
        h2 = sigmoid_f(a3[2]) * tanh_f(c2);                                   \
        c3 = sigmoid_f(a1[3]) * c3 + sigmoid_f(a0[3]) * tanh_f(a2[3]);        \
        h3 = sigmoid_f(a3[3]) * tanh_f(c3);                                   \
        {                                                                     \
            __half2 pa = __floats2half2_rn(h0, h1);                           \
            __half2 pb = __floats2half2_rn(h2, h3);                           \
            uint2 v = { *(unsigned int*)&pa, *(unsigned int*)&pb };           \
            ((uint2*)&hbuf[WBUF][0])[widx] = v;                               \
            *(uint2*)(HIO + ((size_t)(t0 + (ST)) * BATCH + rb) * HID + u0) = v;\
        }                                                                     \
        __builtin_amdgcn_sched_barrier(0);                                    \
        asm volatile("s_waitcnt lgkmcnt(0)");                                 \
        __builtin_amdgcn_sched_barrier(0);                                    \
        __builtin_amdgcn_s_barrier();                                         \
        __builtin_amdgcn_sched_barrier(0);                                    \
    }

    for (int st = 0; st < TC; st += 2) {
        STEP(st,     0, 1, xe);
        STEP(st + 1, 1, 0, xo);
    }
#undef STEP

    f32x4 cv = {c0, c1, c2, c3};
    f32x4 hv = {h0, h1, h2, h3};
    *(f32x4*)(cstate + rb * HID + u0) = cv;
    *(f32x4*)(hstate + rb * HID + u0) = hv;
}

// ---------------- prologue gemm (layer 0, chunk 0) ----------------
__global__ __attribute__((amdgpu_waves_per_eu(2, 2))) __launch_bounds__(512)
void gemm_pre(const float* __restrict__ X, const unsigned short* __restrict__ WG,
              const float* __restrict__ bih, const float* __restrict__ bhh,
              float* __restrict__ XGW)
{
    gemm_path(blockIdx.x, threadIdx.x, 1, X, (const unsigned short*)0, 0, 0,
              WG, bih, bhh, XGW);
}

// ---------------- final FC ----------------
__global__ __launch_bounds__(512)
void fc_kernel(const float* __restrict__ hstate, const float* __restrict__ fcw,
               const float* __restrict__ fcb, float* __restrict__ out)
{
    int idx = threadIdx.x;      // 512 = 256 rows x 2 outs
    int b = idx >> 1, o = idx & 1;
    float acc = fcb[o];
    #pragma unroll
    for (int k = 0; k < HID; ++k)
        acc = fmaf(hstate[b * HID + k], fcw[o * HID + k], acc);
    out[b * 2 + o] = acc;
}

extern "C" void kernel_launch(void* const* d_in, const int* in_sizes, int n_in,
                              void* d_out, int out_size, void* d_ws, size_t ws_size,
                              hipStream_t stream)
{
    const float* x = (const float*)d_in[0];
    const float* w_ih[4]; const float* w_hh[4];
    const float* b_ih[4]; const float* b_hh[4];
    for (int l = 0; l < 4; ++l) {
        w_ih[l] = (const float*)d_in[1 + 4 * l];
        w_hh[l] = (const float*)d_in[2 + 4 * l];
        b_ih[l] = (const float*)d_in[3 + 4 * l];
        b_hh[l] = (const float*)d_in[4 + 4 * l];
    }
    const float* fc_w = (const float*)d_in[17];
    const float* fc_b = (const float*)d_in[18];
    float* out = (float*)d_out;

    char* wsb = (char*)d_ws;
    unsigned short* hio   = (unsigned short*)wsb;                 // 33,554,432 B
    float*          xgA   = (float*)(wsb + 33554432);             // 33,554,432 B
    float*          xgB   = (float*)(wsb + 67108864);             // 33,554,432 B
    float*          hst   = (float*)(wsb + 100663296);            //    131,072 B
    float*          cst   = (float*)(wsb + 100794368);            //    131,072 B
    unsigned short* wih16 = (unsigned short*)(wsb + 100925440);   //    524,288 B
    unsigned short* whh16 = (unsigned short*)(wsb + 101449728);   //    524,288 B
    float* xg[2] = {xgA, xgB};

    pack_whh<<<1024, 256, 0, stream>>>(w_hh[0], w_hh[1], w_hh[2], w_hh[3], whh16);
    pack_wih<<<1024, 256, 0, stream>>>(w_ih[0], w_ih[1], w_ih[2], w_ih[3], wih16);

    // prologue: gemm (layer 0, chunk 0) -> xg[0]
    gemm_pre<<<128, 512, 0, stream>>>(x, wih16, b_ih[0], b_hh[0], xg[0]);

    for (int i = 0; i < 32; ++i) {
        int lyr = i >> 3, c = i & 7, t0 = c * TC;
        int gmode = 0, growoff = 0, gt0 = 0;
        const unsigned short* wg = wih16;
        const float *gbi = b_ih[0], *gbh = b_hh[0];
        if (i + 1 < 32) {
            int nl = (i + 1) >> 3, nc = (i + 1) & 7;
            gt0 = nc * TC;
            gmode = (nl == 0) ? 1 : 2;
            growoff = gt0 * BATCH;
            wg  = wih16 + (size_t)nl * 65536;
            gbi = b_ih[nl];
            gbh = b_hh[nl];
        }
        fused_step<<<144, 512, 0, stream>>>(
            xg[i & 1], xg[(i + 1) & 1],
            whh16 + (size_t)lyr * 65536, hio, hst, cst, t0, (c == 0) ? 1 : 0,
            gmode, x, growoff, gt0, wg, gbi, gbh);
    }
    fc_kernel<<<1, 512, 0, stream>>>(hst, fc_w, fc_b, out);
}

// Round 15
// 2132.228 us; speedup vs baseline: 2.2758x; 1.0903x over previous
//
#include <hip/hip_runtime.h>
#include <hip/hip_fp16.h>

// LSTM: 4 layers, T=512, B=256, INPUT=100, H=128, gates=512 (i,f,g,o)
// Round 14 (= round-12/13 design; DPP direction fixed).
//   r13 failed correctness: used row_shl:8 (0x108, dest[i]=src[i+8]) where
//   the pack needs row_shr:8 (0x118, dest[i]=src[i-8]) -- hi lanes read
//   out-of-row -> 0 -> units 16-31 lost the recurrent term (absmax 2e-2).
//   Design: 32 scan blocks x 8 rows, lane-packed: wave = 4 gates x 32 units
//   (2 sub-tiles); D cols 8-15 garbage; row_shr:8 moves sub-tile 1's valid
//   cols into lanes 8-15 -> all 64 lanes activate 4 real units. Halves
//   per-CU trans/VALU/LDS issue vs r11's 16-CU scan. Layer-3 HIO skipped.
// ws: hio 33.5MB | xgA 33.5MB | xgB 33.5MB | hst/cst 256KB | wih/whh 1MB

#define TSTEPS 512
#define BATCH  256
#define HID    128
#define GATES  512
#define TC     64

typedef _Float16 half8 __attribute__((ext_vector_type(8)));
typedef float f32x4 __attribute__((ext_vector_type(4)));

__device__ __forceinline__ float sigmoid_f(float x) {
    return __builtin_amdgcn_rcpf(1.0f + __expf(-x));
}
__device__ __forceinline__ float tanh_f(float x) {
    float e = __expf(2.0f * x);
    return 1.0f - 2.0f * __builtin_amdgcn_rcpf(e + 1.0f);
}

// ---------------- packs ----------------
__global__ __launch_bounds__(256)
void pack_whh(const float* __restrict__ W0, const float* __restrict__ W1,
              const float* __restrict__ W2, const float* __restrict__ W3,
              unsigned short* __restrict__ out)
{
    int F = blockIdx.x * 256 + threadIdx.x;   // [0, 262144)
    int l = F >> 16;
    int rem = F & 65535;
    const float* W = (l == 0) ? W0 : (l == 1) ? W1 : (l == 2) ? W2 : W3;
    out[F] = __half_as_ushort(__float2half_rn(W[rem]));
}

__global__ __launch_bounds__(256)
void pack_wih(const float* __restrict__ W0, const float* __restrict__ W1,
              const float* __restrict__ W2, const float* __restrict__ W3,
              unsigned short* __restrict__ out)
{
    int F = blockIdx.x * 256 + threadIdx.x;   // [0, 262144)
    int l = F >> 16;
    int rem = F & 65535;
    int row = rem >> 7, kk = rem & 127;
    float v;
    if (l == 0) {
        v = (kk < 100) ? W0[row * 100 + kk] : 0.f;
    } else {
        const float* W = (l == 1) ? W1 : (l == 2) ? W2 : W3;
        v = W[row * 128 + kk];
    }
    out[F] = __half_as_ushort(__float2half_rn(v));
}

// ---------------- gemm device path (128 rows/block, 512 thr) -------------
__device__ __forceinline__ void gemm_path(
    int gb, int tid, int mode,
    const float* __restrict__ X, const unsigned short* __restrict__ HIO,
    int rowoff, int t0n,
    const unsigned short* __restrict__ WG,
    const float* __restrict__ bih, const float* __restrict__ bhh,
    float* __restrict__ XGW)
{
    const int w = tid >> 6, l = tid & 63, s = l >> 4, t15 = l & 15;
    const int r = gb * 128 + w * 16 + t15;   // chunk-local row, [0,16384)

    half8 af[4];
    if (mode == 1) {
        int q = r >> 8, b = r & 255;
        const float* src = X + ((size_t)b * TSTEPS + (t0n + q)) * 100;
        #pragma unroll
        for (int kt = 0; kt < 4; ++kt) {
            half8 h;
            #pragma unroll
            for (int e = 0; e < 8; ++e) {
                int k = kt * 32 + s * 8 + e;
                float v = (k < 100) ? src[k] : 0.f;
                h[e] = (_Float16)v;
            }
            af[kt] = h;
        }
    } else {
        const unsigned short* arow = HIO + ((size_t)(rowoff + r)) * 128 + s * 8;
        #pragma unroll
        for (int kt = 0; kt < 4; ++kt)
            af[kt] = *(const half8*)(arow + kt * 32);
    }

    #pragma unroll 1
    for (int cg = 0; cg < 4; ++cg) {       // 4 col groups of 128
        f32x4 acc[8];
        #pragma unroll
        for (int jt = 0; jt < 8; ++jt) {
            int j = cg * 128 + jt * 16 + t15;
            float bs = bih[j] + bhh[j];
            acc[jt] = (f32x4){bs, bs, bs, bs};
        }
        #pragma unroll
        for (int kt = 0; kt < 4; ++kt) {
            #pragma unroll
            for (int jt = 0; jt < 8; ++jt) {
                half8 bf = *(const half8*)(WG + (size_t)(cg * 128 + jt * 16 + t15) * 128 + kt * 32 + s * 8);
                acc[jt] = __builtin_amdgcn_mfma_f32_16x16x32_f16(af[kt], bf, acc[jt], 0, 0, 0);
            }
        }
        const int rr = gb * 128 + w * 16 + s * 4;
        #pragma unroll
        for (int jt = 0; jt < 8; ++jt) {
            int j = cg * 128 + jt * 16 + t15;
            #pragma unroll
            for (int rg = 0; rg < 4; ++rg)
                XGW[(size_t)(rr + rg) * GATES + j] = acc[jt][rg];
        }
    }
}

// ---------------- fused: scan(chunk c) + gemm(chunk c+1) ----------------
// blocks 0..31: scan, 8 batch rows each; waves 0-3 work, 4-7 barrier-spin.
// blocks 32..159: gemm_path into the other xg buffer.
__global__ __attribute__((amdgpu_waves_per_eu(2, 2))) __launch_bounds__(512)
void fused_step(const float* __restrict__ XGR, float* __restrict__ XGW,
                const unsigned short* __restrict__ WH,
                unsigned short* __restrict__ HIO,
                float* __restrict__ hstate, float* __restrict__ cstate,
                int t0, int first, int wrh,
                int gmode, const float* __restrict__ X, int growoff, int gt0,
                const unsigned short* __restrict__ WG,
                const float* __restrict__ gbih, const float* __restrict__ gbhh)
{
    __shared__ uint4 hbuf[2][256];   // h^T tile (rows 0-7 used), 16B chunks

    if (blockIdx.x >= 32) {
        if (gmode)
            gemm_path(blockIdx.x - 32, threadIdx.x, gmode, X, HIO, growoff,
                      gt0, WG, gbih, gbhh, XGW);
        return;
    }

    const int tid = threadIdx.x;
    if (tid >= 256) {                 // barrier companions (waves 4-7)
        __builtin_amdgcn_s_barrier();
        for (int st = 0; st < TC; ++st)
            __builtin_amdgcn_s_barrier();
        return;
    }

    // ---- scan path: wave w = units [32w,32w+32) x 4 gates, 8 rows ----
    const int w   = tid >> 6;
    const int l   = tid & 63;
    const int s   = l >> 4;
    const int t15 = l & 15;
    const int hi  = t15 >> 3;         // unit sub-tile select after packing
    const int row = t15 & 7;
    const int rb  = blockIdx.x * 8 + row;
    const int u0  = 32 * w + 16 * hi + 4 * s;   // this lane's 4 units

    // A-frags: [g][usub][kt] : A-row = t15 -> unit 32w+16usub+t15
    half8 wA[4][2][4];
    #pragma unroll
    for (int g = 0; g < 4; ++g)
        #pragma unroll
        for (int us = 0; us < 2; ++us)
            #pragma unroll
            for (int kt = 0; kt < 4; ++kt) {
                int rowu = g * 128 + 32 * w + 16 * us + t15;
                wA[g][us][kt] = *(const half8*)(WH + rowu * 128 + kt * 32 + s * 8);
            }

    float c0, c1, c2, c3, h0, h1, h2, h3;
    if (first) {
        c0 = c1 = c2 = c3 = 0.f;
        h0 = h1 = h2 = h3 = 0.f;
    } else {
        f32x4 cv = *(const f32x4*)(cstate + rb * HID + u0);
        c0 = cv[0]; c1 = cv[1]; c2 = cv[2]; c3 = cv[3];
        f32x4 hv = *(const f32x4*)(hstate + rb * HID + u0);
        h0 = hv[0]; h1 = hv[1]; h2 = hv[2]; h3 = hv[3];
    }

    // LDS write (uint2 idx): 16B chunk = u0>>3, XOR-swizzled by row
    const int wchunk = 4 * w + 2 * hi + (s >> 1);
    const int widx = row * 32 + ((wchunk ^ row) << 1) + (s & 1);
    // LDS read (uint4 idx): chunk 4kt+s at col t15
    int ridx[4];
    #pragma unroll
    for (int kt = 0; kt < 4; ++kt)
        ridx[kt] = t15 * 16 + ((4 * kt + s) ^ (t15 & 7));

    {   // initial h -> hbuf[0]
        __half2 pa = __floats2half2_rn(h0, h1);
        __half2 pb = __floats2half2_rn(h2, h3);
        uint2 v = { *(unsigned int*)&pa, *(unsigned int*)&pb };
        ((uint2*)&hbuf[0][0])[widx] = v;
    }
    asm volatile("s_waitcnt lgkmcnt(0)");
    __builtin_amdgcn_sched_barrier(0);
    __builtin_amdgcn_s_barrier();
    __builtin_amdgcn_sched_barrier(0);

    // xg: per-lane loads (row rb, gates g*128 + u0)
    const float* xgp = XGR + (size_t)rb * GATES + u0;
    f32x4 xe[4], xo[4];
    #pragma unroll
    for (int g = 0; g < 4; ++g) xe[g] = *(const f32x4*)(xgp + g * 128);
    #pragma unroll
    for (int g = 0; g < 4; ++g) xo[g] = *(const f32x4*)(xgp + 131072 + g * 128);

// row_shr:8 (0x118): dest[i] = src[i-8] within each 16-lane row -> lanes
// 8-15 receive sub-tile-1's valid cols held by lanes 0-7. bound_ctrl=0.
#define DPP8(x) __int_as_float(__builtin_amdgcn_mov_dpp(__float_as_int(x), 0x118, 0xF, 0xF, true))

#define STEP(ST, RBUF, WBUF, XF)                                              \
    {                                                                         \
        half8 bf0 = __builtin_bit_cast(half8, hbuf[RBUF][ridx[0]]);           \
        half8 bf1 = __builtin_bit_cast(half8, hbuf[RBUF][ridx[1]]);           \
        half8 bf2 = __builtin_bit_cast(half8, hbuf[RBUF][ridx[2]]);           \
        half8 bf3 = __builtin_bit_cast(half8, hbuf[RBUF][ridx[3]]);           \
        f32x4 acc[4][2];                                                      \
        _Pragma("unroll")                                                     \
        for (int g = 0; g < 4; ++g) {                                         \
            acc[g][0] = (f32x4){0.f, 0.f, 0.f, 0.f};                          \
            acc[g][1] = (f32x4){0.f, 0.f, 0.f, 0.f};                          \
        }                                                                     \
        _Pragma("unroll")                                                     \
        for (int g = 0; g < 4; ++g) {                                         \
            acc[g][0] = __builtin_amdgcn_mfma_f32_16x16x32_f16(wA[g][0][0], bf0, acc[g][0], 0, 0, 0); \
            acc[g][1] = __builtin_amdgcn_mfma_f32_16x16x32_f16(wA[g][1][0], bf0, acc[g][1], 0, 0, 0); \
            acc[g][0] = __builtin_amdgcn_mfma_f32_16x16x32_f16(wA[g][0][1], bf1, acc[g][0], 0, 0, 0); \
            acc[g][1] = __builtin_amdgcn_mfma_f32_16x16x32_f16(wA[g][1][1], bf1, acc[g][1], 0, 0, 0); \
            acc[g][0] = __builtin_amdgcn_mfma_f32_16x16x32_f16(wA[g][0][2], bf2, acc[g][0], 0, 0, 0); \
            acc[g][1] = __builtin_amdgcn_mfma_f32_16x16x32_f16(wA[g][1][2], bf2, acc[g][1], 0, 0, 0); \
            acc[g][0] = __builtin_amdgcn_mfma_f32_16x16x32_f16(wA[g][0][3], bf3, acc[g][0], 0, 0, 0); \
            acc[g][1] = __builtin_amdgcn_mfma_f32_16x16x32_f16(wA[g][1][3], bf3, acc[g][1], 0, 0, 0); \
        }                                                                     \
        float pre[4][4];                                                      \
        _Pragma("unroll")                                                     \
        for (int g = 0; g < 4; ++g) {                                         \
            _Pragma("unroll")                                                 \
            for (int r = 0; r < 4; ++r) {                                     \
                float sh = DPP8(acc[g][1][r]);                                \
                pre[g][r] = (hi ? sh : acc[g][0][r]) + XF[g][r];              \
            }                                                                 \
        }                                                                     \
        if ((ST) + 2 < TC) {                                                  \
            const float* xp = xgp + (size_t)((ST) + 2) * 131072;              \
            XF[0] = *(const f32x4*)(xp);                                      \
            XF[1] = *(const f32x4*)(xp + 128);                                \
            XF[2] = *(const f32x4*)(xp + 256);                                \
            XF[3] = *(const f32x4*)(xp + 384);                                \
        }                                                                     \
        c0 = sigmoid_f(pre[1][0]) * c0 + sigmoid_f(pre[0][0]) * tanh_f(pre[2][0]); \
        h0 = sigmoid_f(pre[3][0]) * tanh_f(c0);                               \
        c1 = sigmoid_f(pre[1][1]) * c1 + sigmoid_f(pre[0][1]) * tanh_f(pre[2][1]); \
        h1 = sigmoid_f(pre[3][1]) * tanh_f(c1);                               \
        c2 = sigmoid_f(pre[1][2]) * c2 + sigmoid_f(pre[0][2]) * tanh_f(pre[2][2]); \
        h2 = sigmoid_f(pre[3][2]) * tanh_f(c2);                               \
        c3 = sigmoid_f(pre[1][3]) * c3 + sigmoid_f(pre[0][3]) * tanh_f(pre[2][3]); \
        h3 = sigmoid_f(pre[3][3]) * tanh_f(c3);                               \
        {                                                                     \
            __half2 pa = __floats2half2_rn(h0, h1);                           \
            __half2 pb = __floats2half2_rn(h2, h3);                           \
            uint2 v = { *(unsigned int*)&pa, *(unsigned int*)&pb };           \
            ((uint2*)&hbuf[WBUF][0])[widx] = v;                               \
            if (wrh)                                                          \
                *(uint2*)(HIO + ((size_t)(t0 + (ST)) * BATCH + rb) * HID + u0) = v; \
        }                                                                     \
        __builtin_amdgcn_sched_barrier(0);                                    \
        asm volatile("s_waitcnt lgkmcnt(0)");                                 \
        __builtin_amdgcn_sched_barrier(0);                                    \
        __builtin_amdgcn_s_barrier();                                         \
        __builtin_amdgcn_sched_barrier(0);                                    \
    }

    for (int st = 0; st < TC; st += 2) {
        STEP(st,     0, 1, xe);
        STEP(st + 1, 1, 0, xo);
    }
#undef STEP
#undef DPP8

    f32x4 cv = {c0, c1, c2, c3};
    f32x4 hv = {h0, h1, h2, h3};
    *(f32x4*)(cstate + rb * HID + u0) = cv;
    *(f32x4*)(hstate + rb * HID + u0) = hv;
}

// ---------------- prologue gemm (layer 0, chunk 0) ----------------
__global__ __attribute__((amdgpu_waves_per_eu(2, 2))) __launch_bounds__(512)
void gemm_pre(const float* __restrict__ X, const unsigned short* __restrict__ WG,
              const float* __restrict__ bih, const float* __restrict__ bhh,
              float* __restrict__ XGW)
{
    gemm_path(blockIdx.x, threadIdx.x, 1, X, (const unsigned short*)0, 0, 0,
              WG, bih, bhh, XGW);
}

// ---------------- final FC ----------------
__global__ __launch_bounds__(512)
void fc_kernel(const float* __restrict__ hstate, const float* __restrict__ fcw,
               const float* __restrict__ fcb, float* __restrict__ out)
{
    int idx = threadIdx.x;      // 512 = 256 rows x 2 outs
    int b = idx >> 1, o = idx & 1;
    float acc = fcb[o];
    #pragma unroll
    for (int k = 0; k < HID; ++k)
        acc = fmaf(hstate[b * HID + k], fcw[o * HID + k], acc);
    out[b * 2 + o] = acc;
}

extern "C" void kernel_launch(void* const* d_in, const int* in_sizes, int n_in,
                              void* d_out, int out_size, void* d_ws, size_t ws_size,
                              hipStream_t stream)
{
    const float* x = (const float*)d_in[0];
    const float* w_ih[4]; const float* w_hh[4];
    const float* b_ih[4]; const float* b_hh[4];
    for (int l = 0; l < 4; ++l) {
        w_ih[l] = (const float*)d_in[1 + 4 * l];
        w_hh[l] = (const float*)d_in[2 + 4 * l];
        b_ih[l] = (const float*)d_in[3 + 4 * l];
        b_hh[l] = (const float*)d_in[4 + 4 * l];
    }
    const float* fc_w = (const float*)d_in[17];
    const float* fc_b = (const float*)d_in[18];
    float* out = (float*)d_out;

    char* wsb = (char*)d_ws;
    unsigned short* hio   = (unsigned short*)wsb;                 // 33,554,432 B
    float*          xgA   = (float*)(wsb + 33554432);             // 33,554,432 B
    float*          xgB   = (float*)(wsb + 67108864);             // 33,554,432 B
    float*          hst   = (float*)(wsb + 100663296);            //    131,072 B
    float*          cst   = (float*)(wsb + 100794368);            //    131,072 B
    unsigned short* wih16 = (unsigned short*)(wsb + 100925440);   //    524,288 B
    unsigned short* whh16 = (unsigned short*)(wsb + 101449728);   //    524,288 B
    float* xg[2] = {xgA, xgB};

    pack_whh<<<1024, 256, 0, stream>>>(w_hh[0], w_hh[1], w_hh[2], w_hh[3], whh16);
    pack_wih<<<1024, 256, 0, stream>>>(w_ih[0], w_ih[1], w_ih[2], w_ih[3], wih16);

    // prologue: gemm (layer 0, chunk 0) -> xg[0]
    gemm_pre<<<128, 512, 0, stream>>>(x, wih16, b_ih[0], b_hh[0], xg[0]);

    for (int i = 0; i < 32; ++i) {
        int lyr = i >> 3, c = i & 7, t0 = c * TC;
        int wrh = (lyr < 3) ? 1 : 0;
        int gmode = 0, growoff = 0, gt0 = 0;
        const unsigned short* wg = wih16;
        const float *gbi = b_ih[0], *gbh = b_hh[0];
        if (i + 1 < 32) {
            int nl = (i + 1) >> 3, nc = (i + 1) & 7;
            gt0 = nc * TC;
            gmode = (nl == 0) ? 1 : 2;
            growoff = gt0 * BATCH;
            wg  = wih16 + (size_t)nl * 65536;
            gbi = b_ih[nl];
            gbh = b_hh[nl];
        }
        fused_step<<<160, 512, 0, stream>>>(
            xg[i & 1], xg[(i + 1) & 1],
            whh16 + (size_t)lyr * 65536, hio, hst, cst, t0, (c == 0) ? 1 : 0, wrh,
            gmode, x, growoff, gt0, wg, gbi, gbh);
    }
    fc_kernel<<<1, 512, 0, stream>>>(hst, fc_w, fc_b, out);
}

// Round 16
// 1444.661 us; speedup vs baseline: 3.3590x; 1.4759x over previous
//
#include <hip/hip_runtime.h>
#include <hip/hip_fp16.h>

// LSTM: 4 layers, T=512, B=256, INPUT=100, H=128, gates=512 (i,f,g,o)
// Round 15: layer-wavefront pipelining.
//   r11/r14 two-point fit: per-step issue ~160cyc, serial LATENCY ~2400cyc
//   -> scan is latency-bound; shorten the SERIAL CHAIN, not the step.
//   scan(l,c) deps: scan(l,c-1), gemm(l,c)<-hio(l-1,c). All (l+c=k) scans
//   are independent -> one launch per wavefront k (up to 4 scans x 32
//   blocks). TC=32, 16 chunks/layer -> critical path = 19 wavefronts
//   (vs 32 serial chunk-scans). Per wavefront: gemm launch (xg for wave k,
//   reads hio slices from wave k-1; launch-order serialized) + scan launch.
//   Inner STEP identical to r14 (abs 4.9e-4 proven).
// ws: xg 4x16.8MB | hio slices 3x2.1MB | hst/cst 4x | wih/whh => ~75.5MB

#define TSTEPS 512
#define BATCH  256
#define HID    128
#define GATES  512
#define TC     32

typedef _Float16 half8 __attribute__((ext_vector_type(8)));
typedef float f32x4 __attribute__((ext_vector_type(4)));

__device__ __forceinline__ float sigmoid_f(float x) {
    return __builtin_amdgcn_rcpf(1.0f + __expf(-x));
}
__device__ __forceinline__ float tanh_f(float x) {
    float e = __expf(2.0f * x);
    return 1.0f - 2.0f * __builtin_amdgcn_rcpf(e + 1.0f);
}

// ---------------- packs ----------------
__global__ __launch_bounds__(256)
void pack_whh(const float* __restrict__ W0, const float* __restrict__ W1,
              const float* __restrict__ W2, const float* __restrict__ W3,
              unsigned short* __restrict__ out)
{
    int F = blockIdx.x * 256 + threadIdx.x;   // [0, 262144)
    int l = F >> 16;
    int rem = F & 65535;
    const float* W = (l == 0) ? W0 : (l == 1) ? W1 : (l == 2) ? W2 : W3;
    out[F] = __half_as_ushort(__float2half_rn(W[rem]));
}

__global__ __launch_bounds__(256)
void pack_wih(const float* __restrict__ W0, const float* __restrict__ W1,
              const float* __restrict__ W2, const float* __restrict__ W3,
              unsigned short* __restrict__ out)
{
    int F = blockIdx.x * 256 + threadIdx.x;   // [0, 262144)
    int l = F >> 16;
    int rem = F & 65535;
    int row = rem >> 7, kk = rem & 127;
    float v;
    if (l == 0) {
        v = (kk < 100) ? W0[row * 100 + kk] : 0.f;
    } else {
        const float* W = (l == 1) ? W1 : (l == 2) ? W2 : W3;
        v = W[row * 128 + kk];
    }
    out[F] = __half_as_ushort(__float2half_rn(v));
}

// ---------------- gemm wavefront: xg(l, c=k-l) for all valid l ----------
// 64 blocks per scan-slot (8192 rows of 128). Layer 0: from f32 x; else
// from f16 hio slice (l-1). Bias as C-init. 512 thr = 8 waves x 16 rows.
__global__ __attribute__((amdgpu_waves_per_eu(2, 2))) __launch_bounds__(512)
void gemm_wave(int k, int lmin,
               const float* __restrict__ X,
               const unsigned short* __restrict__ HIOS,
               const unsigned short* __restrict__ WIH,
               const float* __restrict__ bih0, const float* __restrict__ bih1,
               const float* __restrict__ bih2, const float* __restrict__ bih3,
               const float* __restrict__ bhh0, const float* __restrict__ bhh1,
               const float* __restrict__ bhh2, const float* __restrict__ bhh3,
               float* __restrict__ XGB)
{
    const int slot = blockIdx.x >> 6;
    const int gb   = blockIdx.x & 63;
    const int l    = lmin + slot;
    const int c    = k - l;
    const int tid  = threadIdx.x;

    const unsigned short* WG = WIH + (size_t)l * 65536;
    const float* bih = (l == 0) ? bih0 : (l == 1) ? bih1 : (l == 2) ? bih2 : bih3;
    const float* bhh = (l == 0) ? bhh0 : (l == 1) ? bhh1 : (l == 2) ? bhh2 : bhh3;
    float* XGW = XGB + (size_t)l * (TC * BATCH * GATES);

    const int w = tid >> 6, ll = tid & 63, s = ll >> 4, t15 = ll & 15;
    const int r = gb * 128 + w * 16 + t15;   // chunk-local row, [0,8192)

    half8 af[4];
    if (l == 0) {
        int q = r >> 8, b = r & 255;
        const float* src = X + ((size_t)b * TSTEPS + (c * TC + q)) * 100;
        #pragma unroll
        for (int kt = 0; kt < 4; ++kt) {
            half8 h;
            #pragma unroll
            for (int e = 0; e < 8; ++e) {
                int kk = kt * 32 + s * 8 + e;
                float v = (kk < 100) ? src[kk] : 0.f;
                h[e] = (_Float16)v;
            }
            af[kt] = h;
        }
    } else {
        const unsigned short* arow =
            HIOS + (size_t)(l - 1) * (TC * BATCH * HID) + (size_t)r * 128 + s * 8;
        #pragma unroll
        for (int kt = 0; kt < 4; ++kt)
            af[kt] = *(const half8*)(arow + kt * 32);
    }

    #pragma unroll 1
    for (int cg = 0; cg < 4; ++cg) {       // 4 col groups of 128
        f32x4 acc[8];
        #pragma unroll
        for (int jt = 0; jt < 8; ++jt) {
            int j = cg * 128 + jt * 16 + t15;
            float bs = bih[j] + bhh[j];
            acc[jt] = (f32x4){bs, bs, bs, bs};
        }
        #pragma unroll
        for (int kt = 0; kt < 4; ++kt) {
            #pragma unroll
            for (int jt = 0; jt < 8; ++jt) {
                half8 bf = *(const half8*)(WG + (size_t)(cg * 128 + jt * 16 + t15) * 128 + kt * 32 + s * 8);
                acc[jt] = __builtin_amdgcn_mfma_f32_16x16x32_f16(af[kt], bf, acc[jt], 0, 0, 0);
            }
        }
        const int rr = gb * 128 + w * 16 + s * 4;
        #pragma unroll
        for (int jt = 0; jt < 8; ++jt) {
            int j = cg * 128 + jt * 16 + t15;
            #pragma unroll
            for (int rg = 0; rg < 4; ++rg)
                XGW[(size_t)(rr + rg) * GATES + j] = acc[jt][rg];
        }
    }
}

// ---------------- scan wavefront: scan(l, c=k-l) for all valid l --------
// 32 blocks per scan-slot, 8 batch rows each (r14 lane-packed structure).
__global__ __attribute__((amdgpu_waves_per_eu(2, 2))) __launch_bounds__(512)
void scan_wave(int k, int lmin,
               const float* __restrict__ XGB,
               const unsigned short* __restrict__ WHH,
               unsigned short* __restrict__ HIOS,
               float* __restrict__ hstb, float* __restrict__ cstb)
{
    __shared__ uint4 hbuf[2][256];

    const int slot = blockIdx.x >> 5;
    const int blk  = blockIdx.x & 31;
    const int l    = lmin + slot;
    const int c    = k - l;
    const int first = (c == 0);
    const int wrh   = (l < 3);

    const float* XGR = XGB + (size_t)l * (TC * BATCH * GATES);
    const unsigned short* WH = WHH + (size_t)l * 65536;
    unsigned short* HIO = HIOS + (size_t)l * (TC * BATCH * HID);  // slice l
    float* hstate = hstb + (size_t)l * (BATCH * HID);
    float* cstate = cstb + (size_t)l * (BATCH * HID);

    const int tid = threadIdx.x;
    if (tid >= 256) {                 // barrier companions (waves 4-7)
        __builtin_amdgcn_s_barrier();
        for (int st = 0; st < TC; ++st)
            __builtin_amdgcn_s_barrier();
        return;
    }

    const int w   = tid >> 6;
    const int ll  = tid & 63;
    const int s   = ll >> 4;
    const int t15 = ll & 15;
    const int hi  = t15 >> 3;
    const int row = t15 & 7;
    const int rb  = blk * 8 + row;
    const int u0  = 32 * w + 16 * hi + 4 * s;

    // A-frags: A-row = t15 -> unit 32w+16usub+t15
    half8 wA[4][2][4];
    #pragma unroll
    for (int g = 0; g < 4; ++g)
        #pragma unroll
        for (int us = 0; us < 2; ++us)
            #pragma unroll
            for (int kt = 0; kt < 4; ++kt) {
                int rowu = g * 128 + 32 * w + 16 * us + t15;
                wA[g][us][kt] = *(const half8*)(WH + rowu * 128 + kt * 32 + s * 8);
            }

    float c0, c1, c2, c3, h0, h1, h2, h3;
    if (first) {
        c0 = c1 = c2 = c3 = 0.f;
        h0 = h1 = h2 = h3 = 0.f;
    } else {
        f32x4 cv = *(const f32x4*)(cstate + rb * HID + u0);
        c0 = cv[0]; c1 = cv[1]; c2 = cv[2]; c3 = cv[3];
        f32x4 hv = *(const f32x4*)(hstate + rb * HID + u0);
        h0 = hv[0]; h1 = hv[1]; h2 = hv[2]; h3 = hv[3];
    }

    const int wchunk = 4 * w + 2 * hi + (s >> 1);
    const int widx = row * 32 + ((wchunk ^ row) << 1) + (s & 1);
    int ridx[4];
    #pragma unroll
    for (int kt = 0; kt < 4; ++kt)
        ridx[kt] = t15 * 16 + ((4 * kt + s) ^ (t15 & 7));

    {   // initial h -> hbuf[0]
        __half2 pa = __floats2half2_rn(h0, h1);
        __half2 pb = __floats2half2_rn(h2, h3);
        uint2 v = { *(unsigned int*)&pa, *(unsigned int*)&pb };
        ((uint2*)&hbuf[0][0])[widx] = v;
    }
    asm volatile("s_waitcnt lgkmcnt(0)");
    __builtin_amdgcn_sched_barrier(0);
    __builtin_amdgcn_s_barrier();
    __builtin_amdgcn_sched_barrier(0);

    const float* xgp = XGR + (size_t)rb * GATES + u0;
    f32x4 xe[4], xo[4];
    #pragma unroll
    for (int g = 0; g < 4; ++g) xe[g] = *(const f32x4*)(xgp + g * 128);
    #pragma unroll
    for (int g = 0; g < 4; ++g) xo[g] = *(const f32x4*)(xgp + 131072 + g * 128);

// row_shr:8 (0x118): dest[i] = src[i-8] -> lanes 8-15 get sub-tile 1's cols
#define DPP8(x) __int_as_float(__builtin_amdgcn_mov_dpp(__float_as_int(x), 0x118, 0xF, 0xF, true))

#define STEP(ST, RBUF, WBUF, XF)                                              \
    {                                                                         \
        half8 bf0 = __builtin_bit_cast(half8, hbuf[RBUF][ridx[0]]);           \
        half8 bf1 = __builtin_bit_cast(half8, hbuf[RBUF][ridx[1]]);           \
        half8 bf2 = __builtin_bit_cast(half8, hbuf[RBUF][ridx[2]]);           \
        half8 bf3 = __builtin_bit_cast(half8, hbuf[RBUF][ridx[3]]);           \
        f32x4 acc[4][2];                                                      \
        _Pragma("unroll")                                                     \
        for (int g = 0; g < 4; ++g) {                                         \
            acc[g][0] = (f32x4){0.f, 0.f, 0.f, 0.f};                          \
            acc[g][1] = (f32x4){0.f, 0.f, 0.f, 0.f};                          \
        }                                                                     \
        _Pragma("unroll")                                                     \
        for (int g = 0; g < 4; ++g) {                                         \
            acc[g][0] = __builtin_amdgcn_mfma_f32_16x16x32_f16(wA[g][0][0], bf0, acc[g][0], 0, 0, 0); \
            acc[g][1] = __builtin_amdgcn_mfma_f32_16x16x32_f16(wA[g][1][0], bf0, acc[g][1], 0, 0, 0); \
            acc[g][0] = __builtin_amdgcn_mfma_f32_16x16x32_f16(wA[g][0][1], bf1, acc[g][0], 0, 0, 0); \
            acc[g][1] = __builtin_amdgcn_mfma_f32_16x16x32_f16(wA[g][1][1], bf1, acc[g][1], 0, 0, 0); \
            acc[g][0] = __builtin_amdgcn_mfma_f32_16x16x32_f16(wA[g][0][2], bf2, acc[g][0], 0, 0, 0); \
            acc[g][1] = __builtin_amdgcn_mfma_f32_16x16x32_f16(wA[g][1][2], bf2, acc[g][1], 0, 0, 0); \
            acc[g][0] = __builtin_amdgcn_mfma_f32_16x16x32_f16(wA[g][0][3], bf3, acc[g][0], 0, 0, 0); \
            acc[g][1] = __builtin_amdgcn_mfma_f32_16x16x32_f16(wA[g][1][3], bf3, acc[g][1], 0, 0, 0); \
        }                                                                     \
        float pre[4][4];                                                      \
        _Pragma("unroll")                                                     \
        for (int g = 0; g < 4; ++g) {                                         \
            _Pragma("unroll")                                                 \
            for (int r = 0; r < 4; ++r) {                                     \
                float sh = DPP8(acc[g][1][r]);                                \
                pre[g][r] = (hi ? sh : acc[g][0][r]) + XF[g][r];              \
            }                                                                 \
        }                                                                     \
        if ((ST) + 2 < TC) {                                                  \
            const float* xp = xgp + (size_t)((ST) + 2) * 131072;              \
            XF[0] = *(const f32x4*)(xp);                                      \
            XF[1] = *(const f32x4*)(xp + 128);                                \
            XF[2] = *(const f32x4*)(xp + 256);                                \
            XF[3] = *(const f32x4*)(xp + 384);                                \
        }                                                                     \
        c0 = sigmoid_f(pre[1][0]) * c0 + sigmoid_f(pre[0][0]) * tanh_f(pre[2][0]); \
        h0 = sigmoid_f(pre[3][0]) * tanh_f(c0);                               \
        c1 = sigmoid_f(pre[1][1]) * c1 + sigmoid_f(pre[0][1]) * tanh_f(pre[2][1]); \
        h1 = sigmoid_f(pre[3][1]) * tanh_f(c1);                               \
        c2 = sigmoid_f(pre[1][2]) * c2 + sigmoid_f(pre[0][2]) * tanh_f(pre[2][2]); \
        h2 = sigmoid_f(pre[3][2]) * tanh_f(c2);                               \
        c3 = sigmoid_f(pre[1][3]) * c3 + sigmoid_f(pre[0][3]) * tanh_f(pre[2][3]); \
        h3 = sigmoid_f(pre[3][3]) * tanh_f(c3);                               \
        {                                                                     \
            __half2 pa = __floats2half2_rn(h0, h1);                           \
            __half2 pb = __floats2half2_rn(h2, h3);                           \
            uint2 v = { *(unsigned int*)&pa, *(unsigned int*)&pb };           \
            ((uint2*)&hbuf[WBUF][0])[widx] = v;                               \
            if (wrh)                                                          \
                *(uint2*)(HIO + ((size_t)(ST) * BATCH + rb) * HID + u0) = v;  \
        }                                                                     \
        __builtin_amdgcn_sched_barrier(0);                                    \
        asm volatile("s_waitcnt lgkmcnt(0)");                                 \
        __builtin_amdgcn_sched_barrier(0);                                    \
        __builtin_amdgcn_s_barrier();                                         \
        __builtin_amdgcn_sched_barrier(0);                                    \
    }

    for (int st = 0; st < TC; st += 2) {
        STEP(st,     0, 1, xe);
        STEP(st + 1, 1, 0, xo);
    }
#undef STEP
#undef DPP8

    f32x4 cv = {c0, c1, c2, c3};
    f32x4 hv = {h0, h1, h2, h3};
    *(f32x4*)(cstate + rb * HID + u0) = cv;
    *(f32x4*)(hstate + rb * HID + u0) = hv;
}

// ---------------- final FC ----------------
__global__ __launch_bounds__(512)
void fc_kernel(const float* __restrict__ hstate, const float* __restrict__ fcw,
               const float* __restrict__ fcb, float* __restrict__ out)
{
    int idx = threadIdx.x;      // 512 = 256 rows x 2 outs
    int b = idx >> 1, o = idx & 1;
    float acc = fcb[o];
    #pragma unroll
    for (int k = 0; k < HID; ++k)
        acc = fmaf(hstate[b * HID + k], fcw[o * HID + k], acc);
    out[b * 2 + o] = acc;
}

extern "C" void kernel_launch(void* const* d_in, const int* in_sizes, int n_in,
                              void* d_out, int out_size, void* d_ws, size_t ws_size,
                              hipStream_t stream)
{
    const float* x = (const float*)d_in[0];
    const float* w_ih[4]; const float* w_hh[4];
    const float* b_ih[4]; const float* b_hh[4];
    for (int l = 0; l < 4; ++l) {
        w_ih[l] = (const float*)d_in[1 + 4 * l];
        w_hh[l] = (const float*)d_in[2 + 4 * l];
        b_ih[l] = (const float*)d_in[3 + 4 * l];
        b_hh[l] = (const float*)d_in[4 + 4 * l];
    }
    const float* fc_w = (const float*)d_in[17];
    const float* fc_b = (const float*)d_in[18];
    float* out = (float*)d_out;

    char* wsb = (char*)d_ws;
    float*          xg    = (float*)wsb;                          // 67,108,864 B
    unsigned short* hio   = (unsigned short*)(wsb + 67108864);    //  6,291,456 B
    float*          hst   = (float*)(wsb + 73400320);             //    524,288 B
    float*          cst   = (float*)(wsb + 73924608);             //    524,288 B
    unsigned short* wih16 = (unsigned short*)(wsb + 74448896);    //    524,288 B
    unsigned short* whh16 = (unsigned short*)(wsb + 74973184);    //    524,288 B

    pack_whh<<<1024, 256, 0, stream>>>(w_hh[0], w_hh[1], w_hh[2], w_hh[3], whh16);
    pack_wih<<<1024, 256, 0, stream>>>(w_ih[0], w_ih[1], w_ih[2], w_ih[3], wih16);

    // wavefronts k = l + c, l in [0,3], c in [0,15]
    for (int k = 0; k <= 18; ++k) {
        int lmin = (k - 15 > 0) ? k - 15 : 0;
        int lmax = (k < 3) ? k : 3;
        int nv = lmax - lmin + 1;
        gemm_wave<<<nv * 64, 512, 0, stream>>>(
            k, lmin, x, hio, wih16,
            b_ih[0], b_ih[1], b_ih[2], b_ih[3],
            b_hh[0], b_hh[1], b_hh[2], b_hh[3], xg);
        scan_wave<<<nv * 32, 512, 0, stream>>>(k, lmin, xg, whh16, hio, hst, cst);
    }
    fc_kernel<<<1, 512, 0, stream>>>(hst + 3 * BATCH * HID, fc_w, fc_b, out);
}